// Round 9
// baseline (488.089 us; speedup 1.0000x reference)
//
#include <hip/hip_runtime.h>
#include <stdint.h>

typedef __attribute__((ext_vector_type(4))) float f32x4;
typedef __attribute__((ext_vector_type(16))) float f32x16;
typedef __attribute__((ext_vector_type(8))) short bf16x8;
typedef unsigned short u16;

#define MFMA(a, b, c) __builtin_amdgcn_mfma_f32_16x16x32_bf16(a, b, c, 0, 0, 0)
#define MFMA32(a, b, c) __builtin_amdgcn_mfma_f32_32x32x16_bf16(a, b, c, 0, 0, 0)
#define EXP2(x) __builtin_amdgcn_exp2f(x)

__device__ __forceinline__ u16 f2bf(float f) {
  union { float f; unsigned u; } x; x.f = f;
  unsigned r = x.u + 0x7fffu + ((x.u >> 16) & 1u);
  return (u16)(r >> 16);
}

__device__ __forceinline__ unsigned cvtpk(float lo, float hi) {
  unsigned r;
  asm("v_cvt_pk_bf16_f32 %0, %1, %2" : "=v"(r) : "v"(lo), "v"(hi));
  return r;
}

// swap: a[32..63] <-> b[0..31]
__device__ __forceinline__ void pl32swap(unsigned& a, unsigned& b) {
  asm volatile("v_permlane32_swap_b32 %0, %1" : "+v"(a), "+v"(b));
}

__device__ __forceinline__ void gload16(const void* g, void* l) {
  __builtin_amdgcn_global_load_lds(
      (const __attribute__((address_space(1))) unsigned int*)g,
      (__attribute__((address_space(3))) unsigned int*)l, 16, 0, 0);
}

// ---------------------------------------------------------------- cast f32->bf16
__global__ void __launch_bounds__(256) cast_bf16(const float* __restrict__ in,
                                                 u16* __restrict__ out, int n4) {
  int i = blockIdx.x * 256 + threadIdx.x;
  if (i >= n4) return;
  float4 v = reinterpret_cast<const float4*>(in)[i];
  ushort4 o;
  o.x = f2bf(v.x); o.y = f2bf(v.y); o.z = f2bf(v.z); o.w = f2bf(v.w);
  reinterpret_cast<ushort4*>(out)[i] = o;
}

// ---------------------------------------------------------------- GEMM C = A * B^T
// XCD-chunked block remap (T1).
template <int EPI>
__global__ void __launch_bounds__(256, 2)
gemm_bt(const u16* __restrict__ A, const u16* __restrict__ B,
        void* __restrict__ C0, void* __restrict__ C1, void* __restrict__ C2,
        int M, int N, int K, int MB) {
  __shared__ alignas(16) u16 sm[8192];  // A tile [128][32] @0, B tile [128][32] @4096
  const int tid = threadIdx.x;
  const int w = tid >> 6, lane = tid & 63;
  const int lr = lane & 15, g = lane >> 4;
  const int gb = (blockIdx.x & 7) * ((int)gridDim.x >> 3) + (blockIdx.x >> 3);
  const int mb = gb % MB, nb = gb / MB;
  const int m0 = mb * 128, n0 = nb * 128;

  const u16* src[4];
  u16* dst[4];
#pragma unroll
  for (int i = 0; i < 4; ++i) {
    int c = w * 4 + i;
    int r = (c & 7) * 16 + (lane >> 2);
    int sb = (lane & 3) ^ ((r >> 1) & 3);
    src[i] = (c < 8) ? (A + (size_t)(m0 + r) * K + sb * 8)
                     : (B + (size_t)(n0 + r) * K + sb * 8);
    dst[i] = &sm[c * 512];
  }

  f32x4 acc[4][4];
#pragma unroll
  for (int x = 0; x < 4; ++x)
#pragma unroll
    for (int y = 0; y < 4; ++y) acc[x][y] = f32x4{0.f, 0.f, 0.f, 0.f};

  const int rowb = (w >> 1) * 64, colb = (w & 1) * 64;
  const int nk = K >> 5;
  for (int kt = 0; kt < nk; ++kt) {
#pragma unroll
    for (int i = 0; i < 4; ++i) gload16(src[i] + kt * 32, dst[i]);
    __syncthreads();
    bf16x8 af[4], bfr[4];
#pragma unroll
    for (int mi = 0; mi < 4; ++mi) {
      int r = rowb + mi * 16 + lr;
      af[mi] = *(const bf16x8*)((const char*)sm + r * 64 +
                                ((g * 16) ^ (((r >> 1) & 3) << 4)));
    }
#pragma unroll
    for (int ni = 0; ni < 4; ++ni) {
      int r = colb + ni * 16 + lr;
      bfr[ni] = *(const bf16x8*)((const char*)sm + 8192 + r * 64 +
                                 ((g * 16) ^ (((r >> 1) & 3) << 4)));
    }
#pragma unroll
    for (int mi = 0; mi < 4; ++mi)
#pragma unroll
      for (int ni = 0; ni < 4; ++ni)
        acc[mi][ni] = MFMA(af[mi], bfr[ni], acc[mi][ni]);
    __syncthreads();
  }

  // epilogue: C/D layout col = lr, row = g*4 + j (per m89/m91)
  if (EPI == 0) {
    u16* qo = (u16*)C0;
    u16* ko = (u16*)C1;
    u16* vo = (u16*)C2;
#pragma unroll
    for (int mi = 0; mi < 4; ++mi) {
      int s0 = m0 + rowb + mi * 16 + g * 4;
#pragma unroll
      for (int ni = 0; ni < 4; ++ni) {
        int n = n0 + colb + ni * 16 + lr;
        int t = n >> 11, hh = (n >> 7) & 15, d = n & 127;
        if (t == 2) {  // v transposed: [NH][HD][S], 4 consecutive s per lane
          ushort4 pk;
          pk.x = f2bf(acc[mi][ni][0]);
          pk.y = f2bf(acc[mi][ni][1]);
          pk.z = f2bf(acc[mi][ni][2]);
          pk.w = f2bf(acc[mi][ni][3]);
          *(ushort4*)(vo + (size_t)(hh * 128 + d) * 4096 + s0) = pk;
        } else {
          u16* dq = (t == 0 ? qo : ko) + (size_t)(hh * 4096 + s0) * 128 + d;
#pragma unroll
          for (int j = 0; j < 4; ++j) dq[(size_t)j * 128] = f2bf(acc[mi][ni][j]);
        }
      }
    }
  } else {
    float* C = (float*)C0;
#pragma unroll
    for (int mi = 0; mi < 4; ++mi)
#pragma unroll
      for (int ni = 0; ni < 4; ++ni) {
        size_t r0 = (size_t)(m0 + rowb + mi * 16 + g * 4);
        int cn = n0 + colb + ni * 16 + lr;
#pragma unroll
        for (int j = 0; j < 4; ++j) C[(r0 + j) * N + cn] = acc[mi][ni][j];
      }
  }
}

// ---------------------------------------------------------------- flash attention
// In-block split-KV, q=64/wave: 8 waves (512 thr). Waves 0-3: kv[0,2048),
// waves 4-7: kv[2048,4096); wave (w&3) owns 64 q of the same 256-q block.
// 32x32x16 MFMA, in-register P, O^T accumulate, dbuf K/V per group (128KB LDS).
// __launch_bounds__(512) (NO min-waves arg): block size forces 2 waves/SIMD ->
// 256-VGPR cap; kernel needs ~236 (measured R5) -> spill-free. R6 failed ONLY
// because (512,2) budgeted 128 VGPR -> accumulator spills (FETCH 197MB).
// Grid 256 = 1 block/CU, XCD-swizzled. End: waves 4-7 publish (O',m,l) via LDS;
// waves 0-3 merge exactly and store.
__global__ void __launch_bounds__(512)
attn_kernel(const u16* __restrict__ qg, const u16* __restrict__ kg,
            const u16* __restrict__ vtg, u16* __restrict__ og) {
  __shared__ alignas(16) char smb[135168];  // 128 KB staging; 132 KB combine (reused)
  const int tid = threadIdx.x;
  const int w = tid >> 6, lane = tid & 63;
  const int ql = lane & 31, hl = lane >> 5;
  const int bsw = (blockIdx.x & 7) * 32 + (blockIdx.x >> 3);  // XCD swizzle (256=8*32)
  const int h = bsw >> 4;
  const int qb = bsw & 15;
  const int g2 = w >> 2;   // compute kv-group
  const int qw = w & 3;    // q sub-block within group

  // staging roles: w0,1 K-g0 | w2,3 V-g0 | w4,5 K-g1 | w6,7 V-g1 (8 chunks each)
  const u16* ssrc[8];
  unsigned sdst[8];  // byte offsets into smb (buffer 0); buffer 1 = +16384
  size_t sstep;
  {
    const int sg = w >> 2;
    if (!(w & 2)) {  // K stager: tile [64][128] u16
      sstep = 64 * 128;
#pragma unroll
      for (int i = 0; i < 8; ++i) {
        int c = (w & 1) * 8 + i;
        int r = c * 4 + (lane >> 4);         // kv row 0..63 (256B rows)
        int sb = (lane & 15) ^ (r & 7);
        ssrc[i] = kg + (size_t)(h * 4096 + sg * 2048 + r) * 128 + sb * 8;
        sdst[i] = sg * 32768 + c * 1024;
      }
    } else {         // V stager: tile [128][64] u16
      sstep = 64;
#pragma unroll
      for (int i = 0; i < 8; ++i) {
        int c = (w & 1) * 8 + i;
        int r = c * 8 + (lane >> 3);         // d row 0..127 (128B rows)
        int sb = (lane & 7) ^ (r & 7);
        ssrc[i] = vtg + (size_t)(h * 128 + r) * 4096 + sg * 2048 + sb * 8;
        sdst[i] = 65536 + sg * 32768 + c * 1024;
      }
    }
  }

  // Q fragments, B-operand: lane holds col q = qc*32+ql; slice s covers d=s*16+hl*8+(0..7)
  bf16x8 qf[2][8];
#pragma unroll
  for (int qc = 0; qc < 2; ++qc) {
    const u16* qrow =
        qg + (size_t)(h * 4096 + qb * 256 + qw * 64 + qc * 32 + ql) * 128 + hl * 8;
#pragma unroll
    for (int s = 0; s < 8; ++s) qf[qc][s] = *(const bf16x8*)(qrow + s * 16);
  }

  f32x16 of[2][4];
#pragma unroll
  for (int qc = 0; qc < 2; ++qc)
#pragma unroll
    for (int i = 0; i < 4; ++i)
#pragma unroll
      for (int r = 0; r < 16; ++r) of[qc][i][r] = 0.f;
  float mrun[2] = {-1e30f, -1e30f}, lsum[2] = {0.f, 0.f};
  const float sc2 = 0.08838834764831845f * 1.4426950408889634f;
  const float thr = 6.0f / sc2;  // defer-max: P bounded by 2^6

  // prologue: stage tile 0 into buffer 0
#pragma unroll
  for (int i = 0; i < 8; ++i) gload16(ssrc[i], smb + sdst[i]);

  for (int t = 0; t < 32; ++t) {
    const int cur = t & 1;
    asm volatile("s_waitcnt vmcnt(0)" ::: "memory");
    __builtin_amdgcn_s_barrier();
    asm volatile("" ::: "memory");
    if (t + 1 < 32) {
      const int nb = (t + 1) & 1;
#pragma unroll
      for (int i = 0; i < 8; ++i)
        gload16(ssrc[i] + (size_t)(t + 1) * sstep, smb + sdst[i] + nb * 16384);
    }
    const char* kbuf = smb + g2 * 32768 + cur * 16384;
    const char* vbuf = smb + 65536 + g2 * 32768 + cur * 16384;

    // S^T = K * Q^T: each K read feeds 4 MFMAs (2 qc share k-fragment)
    f32x16 st[2][2];
#pragma unroll
    for (int qc = 0; qc < 2; ++qc)
#pragma unroll
      for (int kb = 0; kb < 2; ++kb)
#pragma unroll
        for (int r = 0; r < 16; ++r) st[qc][kb][r] = 0.f;
    const int swz = (ql & 7) << 4;
    __builtin_amdgcn_s_setprio(1);
#pragma unroll
    for (int s = 0; s < 8; ++s) {
      int off = (s * 32 + hl * 16) ^ swz;
      bf16x8 k0 = *(const bf16x8*)(kbuf + ql * 256 + off);
      bf16x8 k1 = *(const bf16x8*)(kbuf + (32 + ql) * 256 + off);
      st[0][0] = MFMA32(k0, qf[0][s], st[0][0]);
      st[0][1] = MFMA32(k1, qf[0][s], st[0][1]);
      st[1][0] = MFMA32(k0, qf[1][s], st[1][0]);
      st[1][1] = MFMA32(k1, qf[1][s], st[1][1]);
    }
    __builtin_amdgcn_s_setprio(0);

    // online softmax per qc (q lane-local; lane^32 holds complementary kv)
    union U { unsigned u[4]; bf16x8 v; };
    U paf[2][4];
#pragma unroll
    for (int qc = 0; qc < 2; ++qc) {
      float tmax = -1e30f;
#pragma unroll
      for (int r = 0; r < 16; ++r)
        tmax = fmaxf(tmax, fmaxf(st[qc][0][r], st[qc][1][r]));
      tmax = fmaxf(tmax, __shfl_xor(tmax, 32));
      if (!__all(tmax - mrun[qc] <= thr)) {  // defer-max
        float mnew = fmaxf(mrun[qc], tmax);
        float esc = EXP2((mrun[qc] - mnew) * sc2);
#pragma unroll
        for (int db = 0; db < 4; ++db)
#pragma unroll
          for (int r = 0; r < 16; ++r) of[qc][db][r] *= esc;
        lsum[qc] *= esc;
        mrun[qc] = mnew;
      }
      float mb2 = mrun[qc] * sc2;
      float psum = 0.f;
      unsigned pk0[8], pk1[8];
#pragma unroll
      for (int i = 0; i < 8; ++i) {
        float a0 = EXP2(st[qc][0][2 * i] * sc2 - mb2);
        float b0 = EXP2(st[qc][0][2 * i + 1] * sc2 - mb2);
        float a1 = EXP2(st[qc][1][2 * i] * sc2 - mb2);
        float b1 = EXP2(st[qc][1][2 * i + 1] * sc2 - mb2);
        psum += (a0 + b0) + (a1 + b1);
        pk0[i] = cvtpk(a0, b0);
        pk1[i] = cvtpk(a1, b1);
      }
      psum += __shfl_xor(psum, 32);
      lsum[qc] += psum;

      pl32swap(pk0[0], pk0[2]); pl32swap(pk0[1], pk0[3]);
      pl32swap(pk0[4], pk0[6]); pl32swap(pk0[5], pk0[7]);
      pl32swap(pk1[0], pk1[2]); pl32swap(pk1[1], pk1[3]);
      pl32swap(pk1[4], pk1[6]); pl32swap(pk1[5], pk1[7]);
#pragma unroll
      for (int i = 0; i < 4; ++i) {
        paf[qc][0].u[i] = pk0[i];
        paf[qc][1].u[i] = pk0[4 + i];
        paf[qc][2].u[i] = pk1[i];
        paf[qc][3].u[i] = pk1[4 + i];
      }
    }

    // O^T += Vt * P^T: each V read feeds 2 MFMAs
    __builtin_amdgcn_s_setprio(1);
#pragma unroll
    for (int db = 0; db < 4; ++db) {
      int rr = db * 32 + ql;
      int vswz = (rr & 7) << 4;
#pragma unroll
      for (int kp = 0; kp < 4; ++kp) {
        bf16x8 vf = *(const bf16x8*)(vbuf + rr * 128 + ((kp * 32 + hl * 16) ^ vswz));
        of[0][db] = MFMA32(vf, paf[0][kp].v, of[0][db]);
        of[1][db] = MFMA32(vf, paf[1][kp].v, of[1][db]);
      }
    }
    __builtin_amdgcn_s_setprio(0);
    asm volatile("" ::: "memory");
  }

  // ---- split-KV merge: waves 4-7 publish (O',m,l); waves 0-3 combine & store
  __syncthreads();
  if (w >= 4) {
    char* base = smb + qw * 33792 + lane * 512;
#pragma unroll
    for (int qc = 0; qc < 2; ++qc)
#pragma unroll
      for (int db = 0; db < 4; ++db)
        *(f32x16*)(base + (qc * 4 + db) * 64) = of[qc][db];
    float4 ml;
    ml.x = mrun[0]; ml.y = lsum[0]; ml.z = mrun[1]; ml.w = lsum[1];
    *(float4*)(smb + qw * 33792 + 32768 + lane * 16) = ml;
  }
  __syncthreads();
  if (w < 4) {
    const char* base = smb + qw * 33792 + lane * 512;
    float4 ml = *(const float4*)(smb + qw * 33792 + 32768 + lane * 16);
#pragma unroll
    for (int qc = 0; qc < 2; ++qc) {
      float mo = (qc == 0) ? ml.x : ml.z;
      float lo = (qc == 0) ? ml.y : ml.w;
      float m = fmaxf(mrun[qc], mo);
      float aa = EXP2((mrun[qc] - m) * sc2);
      float ab = EXP2((mo - m) * sc2);
      float l = lsum[qc] * aa + lo * ab;
      float linv = 1.f / (l + 1e-8f);
      float faa = aa * linv, fab = ab * linv;
      size_t qrow_o = (size_t)(qb * 256 + qw * 64 + qc * 32 + ql) * 2048 + h * 128;
#pragma unroll
      for (int db = 0; db < 4; ++db) {
        f32x16 ob = *(const f32x16*)(base + (qc * 4 + db) * 64);
#pragma unroll
        for (int u = 0; u < 4; ++u) {
          ushort4 pk;
          pk.x = f2bf(of[qc][db][4 * u + 0] * faa + ob[4 * u + 0] * fab);
          pk.y = f2bf(of[qc][db][4 * u + 1] * faa + ob[4 * u + 1] * fab);
          pk.z = f2bf(of[qc][db][4 * u + 2] * faa + ob[4 * u + 2] * fab);
          pk.w = f2bf(of[qc][db][4 * u + 3] * faa + ob[4 * u + 3] * fab);
          *(ushort4*)(og + qrow_o + db * 32 + 8 * u + hl * 4) = pk;
        }
      }
    }
  }
}

// ---------------------------------------------------------------- launcher
extern "C" void kernel_launch(void* const* d_in, const int* in_sizes, int n_in,
                              void* d_out, int out_size, void* d_ws, size_t ws_size,
                              hipStream_t stream) {
  const float* x = (const float*)d_in[0];      // [4096][2048]
  const float* w_qkv = (const float*)d_in[1];  // [6144][2048]
  const float* w_out = (const float*)d_in[2];  // [2048][2048]

  char* ws = (char*)d_ws;
  u16* xb = (u16*)(ws + 0);            // 16 MB
  u16* wqkvb = (u16*)(ws + 16777216);  // 24 MB
  u16* woutb = (u16*)(ws + 41943040);  // 8 MB
  u16* qb = (u16*)(ws + 50331648);     // 16 MB  [NH][S][HD]
  u16* kb = (u16*)(ws + 67108864);     // 16 MB  [NH][S][HD]
  u16* vtb = (u16*)(ws + 83886080);    // 16 MB  [NH][HD][S]
  u16* aob = (u16*)(ws + 100663296);   // 16 MB  [S][H]

  cast_bf16<<<8192, 256, 0, stream>>>(x, xb, 2097152);
  cast_bf16<<<12288, 256, 0, stream>>>(w_qkv, wqkvb, 3145728);
  cast_bf16<<<4096, 256, 0, stream>>>(w_out, woutb, 1048576);

  gemm_bt<0><<<32 * 48, 256, 0, stream>>>(xb, wqkvb, qb, kb, vtb, 4096, 6144, 2048, 32);
  attn_kernel<<<256, 512, 0, stream>>>(qb, kb, vtb, aob);
  gemm_bt<1><<<32 * 16, 256, 0, stream>>>(aob, woutb, d_out, nullptr, nullptr, 4096, 2048, 2048, 32);
}

// Round 10
// 457.046 us; speedup vs baseline: 1.0679x; 1.0679x over previous
//
#include <hip/hip_runtime.h>
#include <stdint.h>

typedef __attribute__((ext_vector_type(4))) float f32x4;
typedef __attribute__((ext_vector_type(16))) float f32x16;
typedef __attribute__((ext_vector_type(8))) short bf16x8;
typedef unsigned short u16;

#define MFMA(a, b, c) __builtin_amdgcn_mfma_f32_16x16x32_bf16(a, b, c, 0, 0, 0)
#define MFMA32(a, b, c) __builtin_amdgcn_mfma_f32_32x32x16_bf16(a, b, c, 0, 0, 0)
#define EXP2(x) __builtin_amdgcn_exp2f(x)

__device__ __forceinline__ u16 f2bf(float f) {
  union { float f; unsigned u; } x; x.f = f;
  unsigned r = x.u + 0x7fffu + ((x.u >> 16) & 1u);
  return (u16)(r >> 16);
}

__device__ __forceinline__ unsigned cvtpk(float lo, float hi) {
  unsigned r;
  asm("v_cvt_pk_bf16_f32 %0, %1, %2" : "=v"(r) : "v"(lo), "v"(hi));
  return r;
}

// swap: a[32..63] <-> b[0..31]
__device__ __forceinline__ void pl32swap(unsigned& a, unsigned& b) {
  asm volatile("v_permlane32_swap_b32 %0, %1" : "+v"(a), "+v"(b));
}

__device__ __forceinline__ void gload16(const void* g, void* l) {
  __builtin_amdgcn_global_load_lds(
      (const __attribute__((address_space(1))) unsigned int*)g,
      (__attribute__((address_space(3))) unsigned int*)l, 16, 0, 0);
}

// ---------------------------------------------------------------- cast f32->bf16
__global__ void __launch_bounds__(256) cast_bf16(const float* __restrict__ in,
                                                 u16* __restrict__ out, int n4) {
  int i = blockIdx.x * 256 + threadIdx.x;
  if (i >= n4) return;
  float4 v = reinterpret_cast<const float4*>(in)[i];
  ushort4 o;
  o.x = f2bf(v.x); o.y = f2bf(v.y); o.z = f2bf(v.z); o.w = f2bf(v.w);
  reinterpret_cast<ushort4*>(out)[i] = o;
}

// ---------------------------------------------------------------- GEMM C = A * B^T
// XCD-chunked block remap (T1).
template <int EPI>
__global__ void __launch_bounds__(256, 2)
gemm_bt(const u16* __restrict__ A, const u16* __restrict__ B,
        void* __restrict__ C0, void* __restrict__ C1, void* __restrict__ C2,
        int M, int N, int K, int MB) {
  __shared__ alignas(16) u16 sm[8192];  // A tile [128][32] @0, B tile [128][32] @4096
  const int tid = threadIdx.x;
  const int w = tid >> 6, lane = tid & 63;
  const int lr = lane & 15, g = lane >> 4;
  const int gb = (blockIdx.x & 7) * ((int)gridDim.x >> 3) + (blockIdx.x >> 3);
  const int mb = gb % MB, nb = gb / MB;
  const int m0 = mb * 128, n0 = nb * 128;

  const u16* src[4];
  u16* dst[4];
#pragma unroll
  for (int i = 0; i < 4; ++i) {
    int c = w * 4 + i;
    int r = (c & 7) * 16 + (lane >> 2);
    int sb = (lane & 3) ^ ((r >> 1) & 3);
    src[i] = (c < 8) ? (A + (size_t)(m0 + r) * K + sb * 8)
                     : (B + (size_t)(n0 + r) * K + sb * 8);
    dst[i] = &sm[c * 512];
  }

  f32x4 acc[4][4];
#pragma unroll
  for (int x = 0; x < 4; ++x)
#pragma unroll
    for (int y = 0; y < 4; ++y) acc[x][y] = f32x4{0.f, 0.f, 0.f, 0.f};

  const int rowb = (w >> 1) * 64, colb = (w & 1) * 64;
  const int nk = K >> 5;
  for (int kt = 0; kt < nk; ++kt) {
#pragma unroll
    for (int i = 0; i < 4; ++i) gload16(src[i] + kt * 32, dst[i]);
    __syncthreads();
    bf16x8 af[4], bfr[4];
#pragma unroll
    for (int mi = 0; mi < 4; ++mi) {
      int r = rowb + mi * 16 + lr;
      af[mi] = *(const bf16x8*)((const char*)sm + r * 64 +
                                ((g * 16) ^ (((r >> 1) & 3) << 4)));
    }
#pragma unroll
    for (int ni = 0; ni < 4; ++ni) {
      int r = colb + ni * 16 + lr;
      bfr[ni] = *(const bf16x8*)((const char*)sm + 8192 + r * 64 +
                                 ((g * 16) ^ (((r >> 1) & 3) << 4)));
    }
#pragma unroll
    for (int mi = 0; mi < 4; ++mi)
#pragma unroll
      for (int ni = 0; ni < 4; ++ni)
        acc[mi][ni] = MFMA(af[mi], bfr[ni], acc[mi][ni]);
    __syncthreads();
  }

  // epilogue: C/D layout col = lr, row = g*4 + j (per m89/m91)
  if (EPI == 0) {
    u16* qo = (u16*)C0;
    u16* ko = (u16*)C1;
    u16* vo = (u16*)C2;
#pragma unroll
    for (int mi = 0; mi < 4; ++mi) {
      int s0 = m0 + rowb + mi * 16 + g * 4;
#pragma unroll
      for (int ni = 0; ni < 4; ++ni) {
        int n = n0 + colb + ni * 16 + lr;
        int t = n >> 11, hh = (n >> 7) & 15, d = n & 127;
        if (t == 2) {  // v transposed: [NH][HD][S], 4 consecutive s per lane
          ushort4 pk;
          pk.x = f2bf(acc[mi][ni][0]);
          pk.y = f2bf(acc[mi][ni][1]);
          pk.z = f2bf(acc[mi][ni][2]);
          pk.w = f2bf(acc[mi][ni][3]);
          *(ushort4*)(vo + (size_t)(hh * 128 + d) * 4096 + s0) = pk;
        } else {
          u16* dq = (t == 0 ? qo : ko) + (size_t)(hh * 4096 + s0) * 128 + d;
#pragma unroll
          for (int j = 0; j < 4; ++j) dq[(size_t)j * 128] = f2bf(acc[mi][ni][j]);
        }
      }
    }
  } else {
    float* C = (float*)C0;
#pragma unroll
    for (int mi = 0; mi < 4; ++mi)
#pragma unroll
      for (int ni = 0; ni < 4; ++ni) {
        size_t r0 = (size_t)(m0 + rowb + mi * 16 + g * 4);
        int cn = n0 + colb + ni * 16 + lr;
#pragma unroll
        for (int j = 0; j < 4; ++j) C[(r0 + j) * N + cn] = acc[mi][ni][j];
      }
  }
}

// ---------------------------------------------------------------- flash attention
// R7 structure (182us proven) minus V-staging: V is L2-resident (XCD swizzle) and
// read straight to registers (16x16B per wave-iter), issued at iteration top and
// consumed in PV ~1200cyc later -> latency hidden. LDS holds only K (dbuf 2x16KB).
// K swizzle upgraded 3b->4b XOR (16 blocks/row): 2 lanes/bank = conflict-free.
// Counted vmcnt (T4): vmcnt(16) before barrier (K landed, V in flight);
// vmcnt(4) before PV (V landed, next K staging in flight). One barrier/iter.
__global__ void __launch_bounds__(256, 2)
attn_kernel(const u16* __restrict__ qg, const u16* __restrict__ kg,
            const u16* __restrict__ vtg, u16* __restrict__ og) {
  __shared__ alignas(16) u16 sm[16384];  // K dbuf: 2 x [64 rows][128 u16] = 2x16KB
  const int tid = threadIdx.x;
  const int w = tid >> 6, lane = tid & 63;
  const int ql = lane & 31, hl = lane >> 5;
  const int gb = (blockIdx.x & 7) * 64 + (blockIdx.x >> 3);  // XCD swizzle (512=8*64)
  const int h = gb >> 5;
  const int qb = gb & 31;

  // K staging: 16 chunks of 1KB per tile; wave w stages chunks 4w..4w+3.
  // chunk c: rows c*4..c*4+3 (256B rows); lane l writes row c*4+(l>>4), block l&15.
  // 4-bit XOR swizzle: LDS block b of row r holds source block b ^ (r&15).
  const u16* ssrc[4];
  u16* sdst[4];
#pragma unroll
  for (int i = 0; i < 4; ++i) {
    int c = w * 4 + i;
    int r = c * 4 + (lane >> 4);
    int sb = (lane & 15) ^ (r & 15);
    ssrc[i] = kg + (size_t)(h * 4096 + r) * 128 + sb * 8;
    sdst[i] = &sm[c * 512];
  }

  // V row bases (global, [NH][HD][S]): lane reads Vt[h][db*32+ql][t*64 + kp*16 + hl*8]
  const u16* vbase[4];
#pragma unroll
  for (int db = 0; db < 4; ++db)
    vbase[db] = vtg + (size_t)(h * 128 + db * 32 + ql) * 4096 + hl * 8;

  // Q fragments, B-operand of 32x32x16: lane holds col q=ql, d-slice s = hl*8+(0..7)
  const u16* qrow = qg + (size_t)(h * 4096 + qb * 128 + w * 32 + ql) * 128 + hl * 8;
  bf16x8 qf[8];
#pragma unroll
  for (int s = 0; s < 8; ++s) qf[s] = *(const bf16x8*)(qrow + s * 16);

  f32x16 of[4];
#pragma unroll
  for (int i = 0; i < 4; ++i)
#pragma unroll
    for (int r = 0; r < 16; ++r) of[i][r] = 0.f;
  float mrun = -1e30f, lsum = 0.f;
  const float sc2 = 0.08838834764831845f * 1.4426950408889634f;
  const float thr = 6.0f / sc2;  // defer-max: P bounded by 2^6

  // prologue: stage K tile 0 into buffer 0
#pragma unroll
  for (int i = 0; i < 4; ++i) gload16(ssrc[i], sdst[i]);

  const int kxor = (ql & 15) << 4;
  for (int t = 0; t < 64; ++t) {
    const int cur = t & 1;

    // V(t) -> registers (oldest-first vmcnt semantics make the counts below exact)
    bf16x8 vfr[4][4];
#pragma unroll
    for (int db = 0; db < 4; ++db)
#pragma unroll
      for (int kp = 0; kp < 4; ++kp)
        vfr[db][kp] = *(const bf16x8*)(vbase[db] + t * 64 + kp * 16);

    // K(t) landed (4 oldest); V(t)'s 16 still in flight
    asm volatile("s_waitcnt vmcnt(16)" ::: "memory");
    __builtin_amdgcn_s_barrier();

    // stage K(t+1) into other buffer (t=63: redundant restage of tile 0, harmless)
    {
      const int tn = (t + 1) & 63;
      const int nb = cur ^ 1;
#pragma unroll
      for (int i = 0; i < 4; ++i)
        gload16(ssrc[i] + (size_t)tn * 8192, sdst[i] + nb * 8192);
    }
    const char* kbuf = (const char*)sm + cur * 16384;

    // S^T = K * Q^T: lane owns q-col ql; rows = k
    f32x16 st0, st1;
#pragma unroll
    for (int r = 0; r < 16; ++r) { st0[r] = 0.f; st1[r] = 0.f; }
    __builtin_amdgcn_s_setprio(1);
#pragma unroll
    for (int s = 0; s < 8; ++s) {
      int off = ((s * 2 + hl) << 4) ^ kxor;
      bf16x8 k0 = *(const bf16x8*)(kbuf + ql * 256 + off);
      bf16x8 k1 = *(const bf16x8*)(kbuf + (32 + ql) * 256 + off);
      st0 = MFMA32(k0, qf[s], st0);
      st1 = MFMA32(k1, qf[s], st1);
    }
    __builtin_amdgcn_s_setprio(0);

    // online softmax, q = ql lane-local; lane^32 holds complementary k's
    float tmax = -1e30f;
#pragma unroll
    for (int r = 0; r < 16; ++r) tmax = fmaxf(tmax, fmaxf(st0[r], st1[r]));
    tmax = fmaxf(tmax, __shfl_xor(tmax, 32));
    if (!__all(tmax - mrun <= thr)) {  // defer-max: rescale only on real growth
      float mnew = fmaxf(mrun, tmax);
      float esc = EXP2((mrun - mnew) * sc2);
#pragma unroll
      for (int db = 0; db < 4; ++db)
#pragma unroll
        for (int r = 0; r < 16; ++r) of[db][r] *= esc;
      lsum *= esc;
      mrun = mnew;
    }
    float mb2 = mrun * sc2;
    float psum = 0.f;
    unsigned pk0[8], pk1[8];
#pragma unroll
    for (int i = 0; i < 8; ++i) {
      float a0 = EXP2(st0[2 * i] * sc2 - mb2);
      float b0 = EXP2(st0[2 * i + 1] * sc2 - mb2);
      float a1 = EXP2(st1[2 * i] * sc2 - mb2);
      float b1 = EXP2(st1[2 * i + 1] * sc2 - mb2);
      psum += (a0 + b0) + (a1 + b1);
      pk0[i] = cvtpk(a0, b0);
      pk1[i] = cvtpk(a1, b1);
    }
    psum += __shfl_xor(psum, 32);
    lsum += psum;

    // P^T B-fragments in-register
    pl32swap(pk0[0], pk0[2]); pl32swap(pk0[1], pk0[3]);
    pl32swap(pk0[4], pk0[6]); pl32swap(pk0[5], pk0[7]);
    pl32swap(pk1[0], pk1[2]); pl32swap(pk1[1], pk1[3]);
    pl32swap(pk1[4], pk1[6]); pl32swap(pk1[5], pk1[7]);
    union U { unsigned u[4]; bf16x8 v; };
    U paf[4];
#pragma unroll
    for (int i = 0; i < 4; ++i) { paf[0].u[i] = pk0[i]; paf[1].u[i] = pk0[4 + i]; }
#pragma unroll
    for (int i = 0; i < 4; ++i) { paf[2].u[i] = pk1[i]; paf[3].u[i] = pk1[4 + i]; }

    // V(t) done (16 oldest remaining were V); K(t+1)'s 4 still in flight
    asm volatile("s_waitcnt vmcnt(4)" ::: "memory");

    // O^T += Vt * P^T  (all operands in registers)
    __builtin_amdgcn_s_setprio(1);
#pragma unroll
    for (int db = 0; db < 4; ++db)
#pragma unroll
      for (int kp = 0; kp < 4; ++kp)
        of[db] = MFMA32(vfr[db][kp], paf[kp].v, of[db]);
    __builtin_amdgcn_s_setprio(0);
  }

  // epilogue: lane owns q = ql; d = db*32 + (r&3) + 8*(r>>2) + 4*hl
  float linv = 1.f / (lsum + 1e-8f);
  size_t qrow_o = (size_t)(qb * 128 + w * 32 + ql) * 2048 + h * 128;
#pragma unroll
  for (int db = 0; db < 4; ++db)
#pragma unroll
    for (int u = 0; u < 4; ++u) {
      ushort4 pk;
      pk.x = f2bf(of[db][4 * u + 0] * linv);
      pk.y = f2bf(of[db][4 * u + 1] * linv);
      pk.z = f2bf(of[db][4 * u + 2] * linv);
      pk.w = f2bf(of[db][4 * u + 3] * linv);
      *(ushort4*)(og + qrow_o + db * 32 + 8 * u + hl * 4) = pk;
    }
}

// ---------------------------------------------------------------- launcher
extern "C" void kernel_launch(void* const* d_in, const int* in_sizes, int n_in,
                              void* d_out, int out_size, void* d_ws, size_t ws_size,
                              hipStream_t stream) {
  const float* x = (const float*)d_in[0];      // [4096][2048]
  const float* w_qkv = (const float*)d_in[1];  // [6144][2048]
  const float* w_out = (const float*)d_in[2];  // [2048][2048]

  char* ws = (char*)d_ws;
  u16* xb = (u16*)(ws + 0);            // 16 MB
  u16* wqkvb = (u16*)(ws + 16777216);  // 24 MB
  u16* woutb = (u16*)(ws + 41943040);  // 8 MB
  u16* qb = (u16*)(ws + 50331648);     // 16 MB  [NH][S][HD]
  u16* kb = (u16*)(ws + 67108864);     // 16 MB  [NH][S][HD]
  u16* vtb = (u16*)(ws + 83886080);    // 16 MB  [NH][HD][S]
  u16* aob = (u16*)(ws + 100663296);   // 16 MB  [S][H]

  cast_bf16<<<8192, 256, 0, stream>>>(x, xb, 2097152);
  cast_bf16<<<12288, 256, 0, stream>>>(w_qkv, wqkvb, 3145728);
  cast_bf16<<<4096, 256, 0, stream>>>(w_out, woutb, 1048576);

  gemm_bt<0><<<32 * 48, 256, 0, stream>>>(xb, wqkvb, qb, kb, vtb, 4096, 6144, 2048, 32);
  attn_kernel<<<512, 256, 0, stream>>>(qb, kb, vtb, aob);
  gemm_bt<1><<<32 * 16, 256, 0, stream>>>(aob, woutb, d_out, nullptr, nullptr, 4096, 2048, 2048, 32);
}

// Round 11
// 356.821 us; speedup vs baseline: 1.3679x; 1.2809x over previous
//
#include <hip/hip_runtime.h>
#include <stdint.h>

typedef __attribute__((ext_vector_type(4))) float f32x4;
typedef __attribute__((ext_vector_type(16))) float f32x16;
typedef __attribute__((ext_vector_type(8))) short bf16x8;
typedef unsigned short u16;

#define MFMA(a, b, c) __builtin_amdgcn_mfma_f32_16x16x32_bf16(a, b, c, 0, 0, 0)
#define MFMA32(a, b, c) __builtin_amdgcn_mfma_f32_32x32x16_bf16(a, b, c, 0, 0, 0)
#define EXP2(x) __builtin_amdgcn_exp2f(x)

__device__ __forceinline__ u16 f2bf(float f) {
  union { float f; unsigned u; } x; x.f = f;
  unsigned r = x.u + 0x7fffu + ((x.u >> 16) & 1u);
  return (u16)(r >> 16);
}

__device__ __forceinline__ unsigned cvtpk(float lo, float hi) {
  unsigned r;
  asm("v_cvt_pk_bf16_f32 %0, %1, %2" : "=v"(r) : "v"(lo), "v"(hi));
  return r;
}

// swap: a[32..63] <-> b[0..31]
__device__ __forceinline__ void pl32swap(unsigned& a, unsigned& b) {
  asm volatile("v_permlane32_swap_b32 %0, %1" : "+v"(a), "+v"(b));
}

__device__ __forceinline__ void gload16(const void* g, void* l) {
  __builtin_amdgcn_global_load_lds(
      (const __attribute__((address_space(1))) unsigned int*)g,
      (__attribute__((address_space(3))) unsigned int*)l, 16, 0, 0);
}

// ---------------------------------------------------------------- cast f32->bf16
__global__ void __launch_bounds__(256) cast_bf16(const float* __restrict__ in,
                                                 u16* __restrict__ out, int n4) {
  int i = blockIdx.x * 256 + threadIdx.x;
  if (i >= n4) return;
  float4 v = reinterpret_cast<const float4*>(in)[i];
  ushort4 o;
  o.x = f2bf(v.x); o.y = f2bf(v.y); o.z = f2bf(v.z); o.w = f2bf(v.w);
  reinterpret_cast<ushort4*>(out)[i] = o;
}

// ---------------------------------------------------------------- GEMM C = A * B^T
// XCD-chunked block remap (T1). EPI 0 scales the Q output by scale*log2e (in f32,
// before bf16 rounding) so the attention softmax works directly in exp2 domain.
template <int EPI>
__global__ void __launch_bounds__(256, 2)
gemm_bt(const u16* __restrict__ A, const u16* __restrict__ B,
        void* __restrict__ C0, void* __restrict__ C1, void* __restrict__ C2,
        int M, int N, int K, int MB) {
  __shared__ alignas(16) u16 sm[8192];  // A tile [128][32] @0, B tile [128][32] @4096
  const int tid = threadIdx.x;
  const int w = tid >> 6, lane = tid & 63;
  const int lr = lane & 15, g = lane >> 4;
  const int gb = (blockIdx.x & 7) * ((int)gridDim.x >> 3) + (blockIdx.x >> 3);
  const int mb = gb % MB, nb = gb / MB;
  const int m0 = mb * 128, n0 = nb * 128;

  const u16* src[4];
  u16* dst[4];
#pragma unroll
  for (int i = 0; i < 4; ++i) {
    int c = w * 4 + i;
    int r = (c & 7) * 16 + (lane >> 2);
    int sb = (lane & 3) ^ ((r >> 1) & 3);
    src[i] = (c < 8) ? (A + (size_t)(m0 + r) * K + sb * 8)
                     : (B + (size_t)(n0 + r) * K + sb * 8);
    dst[i] = &sm[c * 512];
  }

  f32x4 acc[4][4];
#pragma unroll
  for (int x = 0; x < 4; ++x)
#pragma unroll
    for (int y = 0; y < 4; ++y) acc[x][y] = f32x4{0.f, 0.f, 0.f, 0.f};

  const int rowb = (w >> 1) * 64, colb = (w & 1) * 64;
  const int nk = K >> 5;
  for (int kt = 0; kt < nk; ++kt) {
#pragma unroll
    for (int i = 0; i < 4; ++i) gload16(src[i] + kt * 32, dst[i]);
    __syncthreads();
    bf16x8 af[4], bfr[4];
#pragma unroll
    for (int mi = 0; mi < 4; ++mi) {
      int r = rowb + mi * 16 + lr;
      af[mi] = *(const bf16x8*)((const char*)sm + r * 64 +
                                ((g * 16) ^ (((r >> 1) & 3) << 4)));
    }
#pragma unroll
    for (int ni = 0; ni < 4; ++ni) {
      int r = colb + ni * 16 + lr;
      bfr[ni] = *(const bf16x8*)((const char*)sm + 8192 + r * 64 +
                                 ((g * 16) ^ (((r >> 1) & 3) << 4)));
    }
#pragma unroll
    for (int mi = 0; mi < 4; ++mi)
#pragma unroll
      for (int ni = 0; ni < 4; ++ni)
        acc[mi][ni] = MFMA(af[mi], bfr[ni], acc[mi][ni]);
    __syncthreads();
  }

  // epilogue: C/D layout col = lr, row = g*4 + j (per m89/m91)
  if (EPI == 0) {
    const float qs = 0.08838834764831845f * 1.4426950408889634f;  // scale*log2e
    u16* qo = (u16*)C0;
    u16* ko = (u16*)C1;
    u16* vo = (u16*)C2;
#pragma unroll
    for (int mi = 0; mi < 4; ++mi) {
      int s0 = m0 + rowb + mi * 16 + g * 4;
#pragma unroll
      for (int ni = 0; ni < 4; ++ni) {
        int n = n0 + colb + ni * 16 + lr;
        int t = n >> 11, hh = (n >> 7) & 15, d = n & 127;
        if (t == 2) {  // v transposed: [NH][HD][S], 4 consecutive s per lane
          ushort4 pk;
          pk.x = f2bf(acc[mi][ni][0]);
          pk.y = f2bf(acc[mi][ni][1]);
          pk.z = f2bf(acc[mi][ni][2]);
          pk.w = f2bf(acc[mi][ni][3]);
          *(ushort4*)(vo + (size_t)(hh * 128 + d) * 4096 + s0) = pk;
        } else {
          float sc = (t == 0) ? qs : 1.f;
          u16* dq = (t == 0 ? qo : ko) + (size_t)(hh * 4096 + s0) * 128 + d;
#pragma unroll
          for (int j = 0; j < 4; ++j) dq[(size_t)j * 128] = f2bf(acc[mi][ni][j] * sc);
        }
      }
    }
  } else {
    float* C = (float*)C0;
#pragma unroll
    for (int mi = 0; mi < 4; ++mi)
#pragma unroll
      for (int ni = 0; ni < 4; ++ni) {
        size_t r0 = (size_t)(m0 + rowb + mi * 16 + g * 4);
        int cn = n0 + colb + ni * 16 + lr;
#pragma unroll
        for (int j = 0; j < 4; ++j) C[(r0 + j) * N + cn] = acc[mi][ni][j];
      }
  }
}

// ---------------------------------------------------------------- flash attention
// R7 structure (182us proven): 32x32x16 MFMA, in-register P, O^T accumulate,
// q=32/wave, 4 waves, dbuf K+V in LDS, 512 blocks (2/CU), XCD swizzle, defer-max,
// setprio. New: zero-conflict LDS layouts (R9-proven 4-bit XOR class):
//   K tile [64][256B], slot m of row r holds source block m^(r&15).
//   V tile as 64 PAIR-rows of 256B: row j = d-rows {2j,2j+1} interleaved,
//     slot m holds (e,b) with (e<<3|b) = m^(j&15)   (e = d&1, b = kv 16B-block).
// Q arrives pre-scaled by scale*log2e -> softmax is exp2(st - m) directly.
__global__ void __launch_bounds__(256, 2)
attn_kernel(const u16* __restrict__ qg, const u16* __restrict__ kg,
            const u16* __restrict__ vtg, u16* __restrict__ og) {
  __shared__ alignas(16) u16 sm[32768];  // K dbuf 2x16KB @0, V dbuf 2x16KB @32768B
  const int tid = threadIdx.x;
  const int w = tid >> 6, lane = tid & 63;
  const int ql = lane & 31, hl = lane >> 5;
  const int gb = (blockIdx.x & 7) * 64 + (blockIdx.x >> 3);  // XCD swizzle (512=8*64)
  const int h = gb >> 5;
  const int qb = gb & 31;

  // staging: waves 0,1 -> K tile (16 chunks), waves 2,3 -> V tile (16 chunks)
  const u16* ssrc[8];
  u16* sdst[8];  // buffer-0 dests; buffer 1 = +8192 u16
  size_t sstep;
  if (w < 2) {
    sstep = 64 * 128;  // next 64 kv rows
#pragma unroll
    for (int i = 0; i < 8; ++i) {
      int c = (w & 1) * 8 + i;
      int r = c * 4 + (lane >> 4);           // kv row 0..63 (256B rows)
      int sb = (lane & 15) ^ (r & 15);       // 4-bit XOR (R9-proven, 0 conflicts)
      ssrc[i] = kg + (size_t)(h * 4096 + r) * 128 + sb * 8;
      sdst[i] = &sm[c * 512];
    }
  } else {
    sstep = 64;  // next 64 kv columns of v_t
#pragma unroll
    for (int i = 0; i < 8; ++i) {
      int c = (w & 1) * 8 + i;
      int j = c * 4 + (lane >> 4);           // LDS pair-row 0..63 (256B)
      int x = (lane & 15) ^ (j & 15);
      int e = x >> 3, b = x & 7;
      ssrc[i] = vtg + (size_t)(h * 128 + 2 * j + e) * 4096 + b * 8;
      sdst[i] = &sm[16384 + c * 512];
    }
  }

  // Q fragments, B-operand of 32x32x16: lane holds col q=ql, d-slice s = hl*8+(0..7)
  const u16* qrow = qg + (size_t)(h * 4096 + qb * 128 + w * 32 + ql) * 128 + hl * 8;
  bf16x8 qf[8];
#pragma unroll
  for (int s = 0; s < 8; ++s) qf[s] = *(const bf16x8*)(qrow + s * 16);

  f32x16 of[4];
#pragma unroll
  for (int i = 0; i < 4; ++i)
#pragma unroll
    for (int r = 0; r < 16; ++r) of[i][r] = 0.f;
  float mrun = -1e30f, lsum = 0.f;
  const float thr = 6.0f;  // defer-max (exp2 domain): P bounded by 2^6

  // prologue: stage tile 0 into buffer 0
#pragma unroll
  for (int i = 0; i < 8; ++i) gload16(ssrc[i], sdst[i]);

  const int kxor = (ql & 15) << 4;
  const int ve8 = (ql & 1) << 3, vxor = ql >> 1;
  for (int t = 0; t < 64; ++t) {
    const int cur = t & 1;
    asm volatile("s_waitcnt vmcnt(0)" ::: "memory");
    __builtin_amdgcn_s_barrier();
    asm volatile("" ::: "memory");
    if (t + 1 < 64) {
      const int nb = (t + 1) & 1;
#pragma unroll
      for (int i = 0; i < 8; ++i)
        gload16(ssrc[i] + (size_t)(t + 1) * sstep, sdst[i] + nb * 8192);
    }
    const char* kbuf = (const char*)sm + cur * 16384;
    const char* vbuf = (const char*)sm + 32768 + cur * 16384;

    // S^T = K * Q^T (scores arrive pre-scaled into exp2 domain)
    f32x16 st0, st1;
#pragma unroll
    for (int r = 0; r < 16; ++r) { st0[r] = 0.f; st1[r] = 0.f; }
    __builtin_amdgcn_s_setprio(1);
#pragma unroll
    for (int s = 0; s < 8; ++s) {
      int off = ((s * 2 + hl) << 4) ^ kxor;
      bf16x8 k0 = *(const bf16x8*)(kbuf + ql * 256 + off);
      bf16x8 k1 = *(const bf16x8*)(kbuf + (32 + ql) * 256 + off);
      st0 = MFMA32(k0, qf[s], st0);
      st1 = MFMA32(k1, qf[s], st1);
    }
    __builtin_amdgcn_s_setprio(0);

    // online softmax (exp2 domain), q = ql lane-local
    float tmax = -1e30f;
#pragma unroll
    for (int r = 0; r < 16; ++r) tmax = fmaxf(tmax, fmaxf(st0[r], st1[r]));
    tmax = fmaxf(tmax, __shfl_xor(tmax, 32));
    if (!__all(tmax - mrun <= thr)) {  // defer-max: rescale only on real growth
      float mnew = fmaxf(mrun, tmax);
      float esc = EXP2(mrun - mnew);
#pragma unroll
      for (int db = 0; db < 4; ++db)
#pragma unroll
        for (int r = 0; r < 16; ++r) of[db][r] *= esc;
      lsum *= esc;
      mrun = mnew;
    }
    float psum = 0.f;
    unsigned pk0[8], pk1[8];
#pragma unroll
    for (int i = 0; i < 8; ++i) {
      float a0 = EXP2(st0[2 * i] - mrun);
      float b0 = EXP2(st0[2 * i + 1] - mrun);
      float a1 = EXP2(st1[2 * i] - mrun);
      float b1 = EXP2(st1[2 * i + 1] - mrun);
      psum += (a0 + b0) + (a1 + b1);
      pk0[i] = cvtpk(a0, b0);
      pk1[i] = cvtpk(a1, b1);
    }
    psum += __shfl_xor(psum, 32);
    lsum += psum;

    // P^T B-fragments in-register
    pl32swap(pk0[0], pk0[2]); pl32swap(pk0[1], pk0[3]);
    pl32swap(pk0[4], pk0[6]); pl32swap(pk0[5], pk0[7]);
    pl32swap(pk1[0], pk1[2]); pl32swap(pk1[1], pk1[3]);
    pl32swap(pk1[4], pk1[6]); pl32swap(pk1[5], pk1[7]);
    union U { unsigned u[4]; bf16x8 v; };
    U paf[4];
#pragma unroll
    for (int i = 0; i < 4; ++i) { paf[0].u[i] = pk0[i]; paf[1].u[i] = pk0[4 + i]; }
#pragma unroll
    for (int i = 0; i < 4; ++i) { paf[2].u[i] = pk1[i]; paf[3].u[i] = pk1[4 + i]; }

    // O^T += Vt * P^T   (V from pair-row layout: row j=rr>>1, slot ((e<<3)|b)^(j&15))
    __builtin_amdgcn_s_setprio(1);
#pragma unroll
    for (int db = 0; db < 4; ++db) {
      const char* vrow = vbuf + (db * 16 + vxor) * 256;  // j = db*16 + (ql>>1)
#pragma unroll
      for (int kp = 0; kp < 4; ++kp) {
        int m = (ve8 | (kp * 2 + hl)) ^ vxor;
        bf16x8 vf = *(const bf16x8*)(vrow + m * 16);
        of[db] = MFMA32(vf, paf[kp].v, of[db]);
      }
    }
    __builtin_amdgcn_s_setprio(0);
    asm volatile("" ::: "memory");
  }

  // epilogue: lane owns q = ql; d = db*32 + (r&3) + 8*(r>>2) + 4*hl
  float linv = 1.f / (lsum + 1e-8f);
  size_t qrow_o = (size_t)(qb * 128 + w * 32 + ql) * 2048 + h * 128;
#pragma unroll
  for (int db = 0; db < 4; ++db)
#pragma unroll
    for (int u = 0; u < 4; ++u) {
      ushort4 pk;
      pk.x = f2bf(of[db][4 * u + 0] * linv);
      pk.y = f2bf(of[db][4 * u + 1] * linv);
      pk.z = f2bf(of[db][4 * u + 2] * linv);
      pk.w = f2bf(of[db][4 * u + 3] * linv);
      *(ushort4*)(og + qrow_o + db * 32 + 8 * u + hl * 4) = pk;
    }
}

// ---------------------------------------------------------------- launcher
extern "C" void kernel_launch(void* const* d_in, const int* in_sizes, int n_in,
                              void* d_out, int out_size, void* d_ws, size_t ws_size,
                              hipStream_t stream) {
  const float* x = (const float*)d_in[0];      // [4096][2048]
  const float* w_qkv = (const float*)d_in[1];  // [6144][2048]
  const float* w_out = (const float*)d_in[2];  // [2048][2048]

  char* ws = (char*)d_ws;
  u16* xb = (u16*)(ws + 0);            // 16 MB
  u16* wqkvb = (u16*)(ws + 16777216);  // 24 MB
  u16* woutb = (u16*)(ws + 41943040);  // 8 MB
  u16* qb = (u16*)(ws + 50331648);     // 16 MB  [NH][S][HD] (pre-scaled)
  u16* kb = (u16*)(ws + 67108864);     // 16 MB  [NH][S][HD]
  u16* vtb = (u16*)(ws + 83886080);    // 16 MB  [NH][HD][S]
  u16* aob = (u16*)(ws + 100663296);   // 16 MB  [S][H]

  cast_bf16<<<8192, 256, 0, stream>>>(x, xb, 2097152);
  cast_bf16<<<12288, 256, 0, stream>>>(w_qkv, wqkvb, 3145728);
  cast_bf16<<<4096, 256, 0, stream>>>(w_out, woutb, 1048576);

  gemm_bt<0><<<32 * 48, 256, 0, stream>>>(xb, wqkvb, qb, kb, vtb, 4096, 6144, 2048, 32);
  attn_kernel<<<512, 256, 0, stream>>>(qb, kb, vtb, aob);
  gemm_bt<1><<<32 * 16, 256, 0, stream>>>(aob, woutb, d_out, nullptr, nullptr, 4096, 2048, 2048, 32);
}

// Round 12
// 350.176 us; speedup vs baseline: 1.3938x; 1.0190x over previous
//
#include <hip/hip_runtime.h>
#include <stdint.h>

typedef __attribute__((ext_vector_type(4))) float f32x4;
typedef __attribute__((ext_vector_type(16))) float f32x16;
typedef __attribute__((ext_vector_type(8))) short bf16x8;
typedef unsigned short u16;

#define MFMA(a, b, c) __builtin_amdgcn_mfma_f32_16x16x32_bf16(a, b, c, 0, 0, 0)
#define MFMA32(a, b, c) __builtin_amdgcn_mfma_f32_32x32x16_bf16(a, b, c, 0, 0, 0)
#define EXP2(x) __builtin_amdgcn_exp2f(x)
#define FENCE asm volatile("" ::: "memory")
#define BARRIER do { FENCE; __builtin_amdgcn_s_barrier(); FENCE; } while (0)

__device__ __forceinline__ u16 f2bf(float f) {
  union { float f; unsigned u; } x; x.f = f;
  unsigned r = x.u + 0x7fffu + ((x.u >> 16) & 1u);
  return (u16)(r >> 16);
}

__device__ __forceinline__ unsigned cvtpk(float lo, float hi) {
  unsigned r;
  asm("v_cvt_pk_bf16_f32 %0, %1, %2" : "=v"(r) : "v"(lo), "v"(hi));
  return r;
}

__device__ __forceinline__ void pl32swap(unsigned& a, unsigned& b) {
  asm volatile("v_permlane32_swap_b32 %0, %1" : "+v"(a), "+v"(b));
}

__device__ __forceinline__ void gload16(const void* g, void* l) {
  __builtin_amdgcn_global_load_lds(
      (const __attribute__((address_space(1))) unsigned int*)g,
      (__attribute__((address_space(3))) unsigned int*)l, 16, 0, 0);
}

// ---------------------------------------------------------------- cast f32->bf16
__global__ void __launch_bounds__(256) cast_bf16(const float* __restrict__ in,
                                                 u16* __restrict__ out, int n4) {
  int i = blockIdx.x * 256 + threadIdx.x;
  if (i >= n4) return;
  float4 v = reinterpret_cast<const float4*>(in)[i];
  ushort4 o;
  o.x = f2bf(v.x); o.y = f2bf(v.y); o.z = f2bf(v.z); o.w = f2bf(v.w);
  reinterpret_cast<ushort4*>(out)[i] = o;
}

// ---------------------------------------------------------------- 8-phase 256^2 GEMM
// C = A * B^T. A:[M][K], B:[N][K] bf16. 512 thr / 8 waves (2M x 4N), BK=64,
// wave output 128x64 (acc[8][4]), LDS 128KB: A dbuf 2x32KB @0, B dbuf @65536.
// Slot-XOR layout (zero-conflict, R10-proven class): LDS 16B-slot m of row r holds
// source slot m^(r&7); staging = linear LDS dest (base+lane*16) + pre-swizzled
// global source. 8 phases / 2 K-tiles; counted vmcnt(6) at phases 4,8 only.
// Stage units (16KB each): Ap1 = A rows {0-63,128-191}, Ap2 = +64; Bp1 = B rows
// {0-31,64-95,128-159,192-223}, Bp2 = +32. Unit of tile t lands in dbuf t&1.
// EPI 0: scatter q/k/v_t (Q pre-scaled by scale*log2e).
template <int EPI>
__global__ void __launch_bounds__(512)
gemm8(const u16* __restrict__ A, const u16* __restrict__ B,
      void* __restrict__ C0, void* __restrict__ C1, void* __restrict__ C2,
      int M, int N, int K, int MBt) {
  __shared__ alignas(16) char smb[131072];
  const int tid = threadIdx.x;
  const int w = tid >> 6, lane = tid & 63;
  const int lr = lane & 15, g = lane >> 4;
  const int wm = w >> 2, wn = w & 3;
  const int gb = (blockIdx.x & 7) * ((int)gridDim.x >> 3) + (blockIdx.x >> 3);
  const int mb = gb % MBt, nb = gb / MBt;
  const int m0 = mb * 256, n0 = nb * 256;
  const int NT = K >> 6, NIT = NT >> 1;

  // ---- staging precompute: wave w stages chunks c = 2w, 2w+1 of each unit
  const int l8 = lane >> 3, l7 = lane & 7;
  const int csb = (l7 ^ l8) * 16;  // pre-swizzled source byte col
  const char* asrcb[2];
  const char* bsrcb[2];
  unsigned adst[2], bdst[2];
#pragma unroll
  for (int j = 0; j < 2; ++j) {
    int c = 2 * w + j;
    int ra = (c & 7) * 8 + ((c >> 3) << 7) + l8;   // Ap1 rows {0-63,128-191}
    asrcb[j] = (const char*)(A + (size_t)(m0 + ra) * K) + csb;
    adst[j] = (unsigned)(ra * 128 + l7 * 16);
    int rb = (c & 3) * 8 + ((c >> 2) << 6) + l8;   // Bp1 rows {0-31,64-95,...}
    bsrcb[j] = (const char*)(B + (size_t)(n0 + rb) * K) + csb;
    bdst[j] = (unsigned)(rb * 128 + l7 * 16);
  }
  const size_t arow64 = (size_t)64 * K * 2;  // Ap2 source offset (bytes)
  const size_t brow32 = (size_t)32 * K * 2;  // Bp2

#define STG(kt, u)                                                            \
  do {                                                                        \
    if ((kt) < NT) {                                                          \
      int _d = ((kt) & 1) ? 32768 : 0;                                        \
      size_t _ko = (size_t)(kt) * 128;                                        \
      if ((u) == 0) {                                                         \
        gload16(asrcb[0] + _ko, smb + _d + adst[0]);                          \
        gload16(asrcb[1] + _ko, smb + _d + adst[1]);                          \
      } else if ((u) == 1) {                                                  \
        gload16(bsrcb[0] + _ko, smb + 65536 + _d + bdst[0]);                  \
        gload16(bsrcb[1] + _ko, smb + 65536 + _d + bdst[1]);                  \
      } else if ((u) == 2) {                                                  \
        gload16(asrcb[0] + arow64 + _ko, smb + _d + 8192 + adst[0]);          \
        gload16(asrcb[1] + arow64 + _ko, smb + _d + 8192 + adst[1]);          \
      } else {                                                                \
        gload16(bsrcb[0] + brow32 + _ko, smb + 65536 + _d + 4096 + bdst[0]);  \
        gload16(bsrcb[1] + brow32 + _ko, smb + 65536 + _d + 4096 + bdst[1]);  \
      }                                                                       \
    }                                                                         \
  } while (0)

  // ---- fragment read helpers (zero-conflict slot-XOR reads)
  f32x4 acc[8][4];
#pragma unroll
  for (int x = 0; x < 8; ++x)
#pragma unroll
    for (int y = 0; y < 4; ++y) acc[x][y] = f32x4{0.f, 0.f, 0.f, 0.f};
  bf16x8 af[4][2], bf01[2][2], bf23[2][2];
  const int aoff0 = ((g) ^ (lr & 7)) << 4;        // ks=0 slot
  const int aoff1 = ((4 + g) ^ (lr & 7)) << 4;    // ks=1 slot
  const int arow = (wm * 128 + lr) * 128;
  const int brow = (wn * 64 + lr) * 128;

  auto LDA = [&](const char* base, int mih) {
#pragma unroll
    for (int mi = 0; mi < 4; ++mi) {
      const char* p = base + arow + (mih * 64 + mi * 16) * 128;
      af[mi][0] = *(const bf16x8*)(p + aoff0);
      af[mi][1] = *(const bf16x8*)(p + aoff1);
    }
  };
  auto LDB = [&](const char* base, bf16x8 (*bfr)[2], int nih) {
#pragma unroll
    for (int ni = 0; ni < 2; ++ni) {
      const char* p = base + brow + (nih * 32 + ni * 16) * 128;
      bfr[ni][0] = *(const bf16x8*)(p + aoff0);
      bfr[ni][1] = *(const bf16x8*)(p + aoff1);
    }
  };
  auto MM = [&](int mih, int nih, bf16x8 (*bfr)[2]) {
    __builtin_amdgcn_s_setprio(1);
#pragma unroll
    for (int mi = 0; mi < 4; ++mi)
#pragma unroll
      for (int ni = 0; ni < 2; ++ni) {
        acc[mih * 4 + mi][nih * 2 + ni] =
            MFMA(af[mi][0], bfr[ni][0], acc[mih * 4 + mi][nih * 2 + ni]);
        acc[mih * 4 + mi][nih * 2 + ni] =
            MFMA(af[mi][1], bfr[ni][1], acc[mih * 4 + mi][nih * 2 + ni]);
      }
    __builtin_amdgcn_s_setprio(0);
  };

  // ---- prologue: tile0 fully + tile1 {Ap1,Bp1,Ap2}; wait until tile0 landed
  STG(0, 0); STG(0, 1); STG(0, 2); STG(0, 3);
  STG(1, 0); STG(1, 1); STG(1, 2);
  asm volatile("s_waitcnt vmcnt(6)" ::: "memory");
  BARRIER;

  const char* A0 = smb;
  const char* B0 = smb + 65536;
  const char* A1 = smb + 32768;
  const char* B1 = smb + 65536 + 32768;

  for (int it = 0; it < NIT; ++it) {
    const int t0 = 2 * it;
    const bool lastit = (it == NIT - 1);
    // ph1: Q00 of tile t0 (dbuf0)
    LDA(A0, 0); LDB(B0, bf01, 0); STG(t0 + 1, 3);
    BARRIER; MM(0, 0, bf01); BARRIER;
    // ph2: Q01
    LDB(B0, bf23, 1); STG(t0 + 2, 0);
    BARRIER; MM(0, 1, bf23); BARRIER;
    // ph3: Q11
    LDA(A0, 1); STG(t0 + 2, 1);
    BARRIER; MM(1, 1, bf23); BARRIER;
    // ph4: Q10 (reuse bf01)  + counted drain
    STG(t0 + 2, 2);
    if (lastit) asm volatile("s_waitcnt vmcnt(0)" ::: "memory");
    else        asm volatile("s_waitcnt vmcnt(6)" ::: "memory");
    BARRIER; MM(1, 0, bf01); BARRIER;
    // ph5: Q00 of tile t0+1 (dbuf1)
    LDA(A1, 0); LDB(B1, bf01, 0); STG(t0 + 2, 3);
    BARRIER; MM(0, 0, bf01); BARRIER;
    // ph6: Q01
    LDB(B1, bf23, 1); STG(t0 + 3, 0);
    BARRIER; MM(0, 1, bf23); BARRIER;
    // ph7: Q11
    LDA(A1, 1); STG(t0 + 3, 1);
    BARRIER; MM(1, 1, bf23); BARRIER;
    // ph8: Q10 + counted drain
    STG(t0 + 3, 2);
    asm volatile("s_waitcnt vmcnt(6)" ::: "memory");
    BARRIER; MM(1, 0, bf01); BARRIER;
  }
#undef STG

  // ---- epilogue: C/D layout col = lr, row = g*4 + j
  if (EPI == 0) {
    const float qs = 0.08838834764831845f * 1.4426950408889634f;  // scale*log2e
    u16* qo = (u16*)C0;
    u16* ko = (u16*)C1;
    u16* vo = (u16*)C2;
#pragma unroll
    for (int mi = 0; mi < 8; ++mi) {
      int s0 = m0 + wm * 128 + mi * 16 + g * 4;
#pragma unroll
      for (int ni = 0; ni < 4; ++ni) {
        int n = n0 + wn * 64 + ni * 16 + lr;
        int t = n >> 11, hh = (n >> 7) & 15, d = n & 127;
        if (t == 2) {
          ushort4 pk;
          pk.x = f2bf(acc[mi][ni][0]);
          pk.y = f2bf(acc[mi][ni][1]);
          pk.z = f2bf(acc[mi][ni][2]);
          pk.w = f2bf(acc[mi][ni][3]);
          *(ushort4*)(vo + (size_t)(hh * 128 + d) * 4096 + s0) = pk;
        } else {
          float sc = (t == 0) ? qs : 1.f;
          u16* dq = (t == 0 ? qo : ko) + (size_t)(hh * 4096 + s0) * 128 + d;
#pragma unroll
          for (int j = 0; j < 4; ++j) dq[(size_t)j * 128] = f2bf(acc[mi][ni][j] * sc);
        }
      }
    }
  } else {
    float* C = (float*)C0;
#pragma unroll
    for (int mi = 0; mi < 8; ++mi)
#pragma unroll
      for (int ni = 0; ni < 4; ++ni) {
        size_t r0 = (size_t)(m0 + wm * 128 + mi * 16 + g * 4);
        int cn = n0 + wn * 64 + ni * 16 + lr;
#pragma unroll
        for (int j = 0; j < 4; ++j) C[(r0 + j) * N + cn] = acc[mi][ni][j];
      }
  }
}

// ---------------------------------------------------------------- GEMM 128^2 (m97) for out-proj
template <int EPI>
__global__ void __launch_bounds__(256, 2)
gemm_bt(const u16* __restrict__ A, const u16* __restrict__ B,
        void* __restrict__ C0, void* __restrict__ C1, void* __restrict__ C2,
        int M, int N, int K, int MB) {
  __shared__ alignas(16) u16 sm[8192];
  const int tid = threadIdx.x;
  const int w = tid >> 6, lane = tid & 63;
  const int lr = lane & 15, g = lane >> 4;
  const int gb = (blockIdx.x & 7) * ((int)gridDim.x >> 3) + (blockIdx.x >> 3);
  const int mb = gb % MB, nb = gb / MB;
  const int m0 = mb * 128, n0 = nb * 128;

  const u16* src[4];
  u16* dst[4];
#pragma unroll
  for (int i = 0; i < 4; ++i) {
    int c = w * 4 + i;
    int r = (c & 7) * 16 + (lane >> 2);
    int sb = (lane & 3) ^ ((r >> 1) & 3);
    src[i] = (c < 8) ? (A + (size_t)(m0 + r) * K + sb * 8)
                     : (B + (size_t)(n0 + r) * K + sb * 8);
    dst[i] = &sm[c * 512];
  }

  f32x4 acc[4][4];
#pragma unroll
  for (int x = 0; x < 4; ++x)
#pragma unroll
    for (int y = 0; y < 4; ++y) acc[x][y] = f32x4{0.f, 0.f, 0.f, 0.f};

  const int rowb = (w >> 1) * 64, colb = (w & 1) * 64;
  const int nk = K >> 5;
  for (int kt = 0; kt < nk; ++kt) {
#pragma unroll
    for (int i = 0; i < 4; ++i) gload16(src[i] + kt * 32, dst[i]);
    __syncthreads();
    bf16x8 af[4], bfr[4];
#pragma unroll
    for (int mi = 0; mi < 4; ++mi) {
      int r = rowb + mi * 16 + lr;
      af[mi] = *(const bf16x8*)((const char*)sm + r * 64 +
                                ((g * 16) ^ (((r >> 1) & 3) << 4)));
    }
#pragma unroll
    for (int ni = 0; ni < 4; ++ni) {
      int r = colb + ni * 16 + lr;
      bfr[ni] = *(const bf16x8*)((const char*)sm + 8192 + r * 64 +
                                 ((g * 16) ^ (((r >> 1) & 3) << 4)));
    }
#pragma unroll
    for (int mi = 0; mi < 4; ++mi)
#pragma unroll
      for (int ni = 0; ni < 4; ++ni)
        acc[mi][ni] = MFMA(af[mi], bfr[ni], acc[mi][ni]);
    __syncthreads();
  }

  float* C = (float*)C0;
#pragma unroll
  for (int mi = 0; mi < 4; ++mi)
#pragma unroll
    for (int ni = 0; ni < 4; ++ni) {
      size_t r0 = (size_t)(m0 + rowb + mi * 16 + g * 4);
      int cn = n0 + colb + ni * 16 + lr;
#pragma unroll
      for (int j = 0; j < 4; ++j) C[(r0 + j) * N + cn] = acc[mi][ni][j];
    }
}

// ---------------------------------------------------------------- flash attention (R10, 177us)
__global__ void __launch_bounds__(256, 2)
attn_kernel(const u16* __restrict__ qg, const u16* __restrict__ kg,
            const u16* __restrict__ vtg, u16* __restrict__ og) {
  __shared__ alignas(16) u16 sm[32768];
  const int tid = threadIdx.x;
  const int w = tid >> 6, lane = tid & 63;
  const int ql = lane & 31, hl = lane >> 5;
  const int gb = (blockIdx.x & 7) * 64 + (blockIdx.x >> 3);
  const int h = gb >> 5;
  const int qb = gb & 31;

  const u16* ssrc[8];
  u16* sdst[8];
  size_t sstep;
  if (w < 2) {
    sstep = 64 * 128;
#pragma unroll
    for (int i = 0; i < 8; ++i) {
      int c = (w & 1) * 8 + i;
      int r = c * 4 + (lane >> 4);
      int sb = (lane & 15) ^ (r & 15);
      ssrc[i] = kg + (size_t)(h * 4096 + r) * 128 + sb * 8;
      sdst[i] = &sm[c * 512];
    }
  } else {
    sstep = 64;
#pragma unroll
    for (int i = 0; i < 8; ++i) {
      int c = (w & 1) * 8 + i;
      int j = c * 4 + (lane >> 4);
      int x = (lane & 15) ^ (j & 15);
      int e = x >> 3, b = x & 7;
      ssrc[i] = vtg + (size_t)(h * 128 + 2 * j + e) * 4096 + b * 8;
      sdst[i] = &sm[16384 + c * 512];
    }
  }

  const u16* qrow = qg + (size_t)(h * 4096 + qb * 128 + w * 32 + ql) * 128 + hl * 8;
  bf16x8 qf[8];
#pragma unroll
  for (int s = 0; s < 8; ++s) qf[s] = *(const bf16x8*)(qrow + s * 16);

  f32x16 of[4];
#pragma unroll
  for (int i = 0; i < 4; ++i)
#pragma unroll
    for (int r = 0; r < 16; ++r) of[i][r] = 0.f;
  float mrun = -1e30f, lsum = 0.f;
  const float thr = 6.0f;

#pragma unroll
  for (int i = 0; i < 8; ++i) gload16(ssrc[i], sdst[i]);

  const int kxor = (ql & 15) << 4;
  const int ve8 = (ql & 1) << 3, vxor = ql >> 1;
  for (int t = 0; t < 64; ++t) {
    const int cur = t & 1;
    asm volatile("s_waitcnt vmcnt(0)" ::: "memory");
    __builtin_amdgcn_s_barrier();
    FENCE;
    if (t + 1 < 64) {
      const int nb = (t + 1) & 1;
#pragma unroll
      for (int i = 0; i < 8; ++i)
        gload16(ssrc[i] + (size_t)(t + 1) * sstep, sdst[i] + nb * 8192);
    }
    const char* kbuf = (const char*)sm + cur * 16384;
    const char* vbuf = (const char*)sm + 32768 + cur * 16384;

    f32x16 st0, st1;
#pragma unroll
    for (int r = 0; r < 16; ++r) { st0[r] = 0.f; st1[r] = 0.f; }
    __builtin_amdgcn_s_setprio(1);
#pragma unroll
    for (int s = 0; s < 8; ++s) {
      int off = ((s * 2 + hl) << 4) ^ kxor;
      bf16x8 k0 = *(const bf16x8*)(kbuf + ql * 256 + off);
      bf16x8 k1 = *(const bf16x8*)(kbuf + (32 + ql) * 256 + off);
      st0 = MFMA32(k0, qf[s], st0);
      st1 = MFMA32(k1, qf[s], st1);
    }
    __builtin_amdgcn_s_setprio(0);

    float tmax = -1e30f;
#pragma unroll
    for (int r = 0; r < 16; ++r) tmax = fmaxf(tmax, fmaxf(st0[r], st1[r]));
    tmax = fmaxf(tmax, __shfl_xor(tmax, 32));
    if (!__all(tmax - mrun <= thr)) {
      float mnew = fmaxf(mrun, tmax);
      float esc = EXP2(mrun - mnew);
#pragma unroll
      for (int db = 0; db < 4; ++db)
#pragma unroll
        for (int r = 0; r < 16; ++r) of[db][r] *= esc;
      lsum *= esc;
      mrun = mnew;
    }
    float psum = 0.f;
    unsigned pk0[8], pk1[8];
#pragma unroll
    for (int i = 0; i < 8; ++i) {
      float a0 = EXP2(st0[2 * i] - mrun);
      float b0 = EXP2(st0[2 * i + 1] - mrun);
      float a1 = EXP2(st1[2 * i] - mrun);
      float b1 = EXP2(st1[2 * i + 1] - mrun);
      psum += (a0 + b0) + (a1 + b1);
      pk0[i] = cvtpk(a0, b0);
      pk1[i] = cvtpk(a1, b1);
    }
    psum += __shfl_xor(psum, 32);
    lsum += psum;

    pl32swap(pk0[0], pk0[2]); pl32swap(pk0[1], pk0[3]);
    pl32swap(pk0[4], pk0[6]); pl32swap(pk0[5], pk0[7]);
    pl32swap(pk1[0], pk1[2]); pl32swap(pk1[1], pk1[3]);
    pl32swap(pk1[4], pk1[6]); pl32swap(pk1[5], pk1[7]);
    union U { unsigned u[4]; bf16x8 v; };
    U paf[4];
#pragma unroll
    for (int i = 0; i < 4; ++i) { paf[0].u[i] = pk0[i]; paf[1].u[i] = pk0[4 + i]; }
#pragma unroll
    for (int i = 0; i < 4; ++i) { paf[2].u[i] = pk1[i]; paf[3].u[i] = pk1[4 + i]; }

    __builtin_amdgcn_s_setprio(1);
#pragma unroll
    for (int db = 0; db < 4; ++db) {
      const char* vrow = vbuf + (db * 16 + vxor) * 256;
#pragma unroll
      for (int kp = 0; kp < 4; ++kp) {
        int m = (ve8 | (kp * 2 + hl)) ^ vxor;
        bf16x8 vf = *(const bf16x8*)(vrow + m * 16);
        of[db] = MFMA32(vf, paf[kp].v, of[db]);
      }
    }
    __builtin_amdgcn_s_setprio(0);
    FENCE;
  }

  float linv = 1.f / (lsum + 1e-8f);
  size_t qrow_o = (size_t)(qb * 128 + w * 32 + ql) * 2048 + h * 128;
#pragma unroll
  for (int db = 0; db < 4; ++db)
#pragma unroll
    for (int u = 0; u < 4; ++u) {
      ushort4 pk;
      pk.x = f2bf(of[db][4 * u + 0] * linv);
      pk.y = f2bf(of[db][4 * u + 1] * linv);
      pk.z = f2bf(of[db][4 * u + 2] * linv);
      pk.w = f2bf(of[db][4 * u + 3] * linv);
      *(ushort4*)(og + qrow_o + db * 32 + 8 * u + hl * 4) = pk;
    }
}

// ---------------------------------------------------------------- launcher
extern "C" void kernel_launch(void* const* d_in, const int* in_sizes, int n_in,
                              void* d_out, int out_size, void* d_ws, size_t ws_size,
                              hipStream_t stream) {
  const float* x = (const float*)d_in[0];      // [4096][2048]
  const float* w_qkv = (const float*)d_in[1];  // [6144][2048]
  const float* w_out = (const float*)d_in[2];  // [2048][2048]

  char* ws = (char*)d_ws;
  u16* xb = (u16*)(ws + 0);            // 16 MB
  u16* wqkvb = (u16*)(ws + 16777216);  // 24 MB
  u16* woutb = (u16*)(ws + 41943040);  // 8 MB
  u16* qb = (u16*)(ws + 50331648);     // 16 MB  [NH][S][HD] (pre-scaled)
  u16* kb = (u16*)(ws + 67108864);     // 16 MB  [NH][S][HD]
  u16* vtb = (u16*)(ws + 83886080);    // 16 MB  [NH][HD][S]
  u16* aob = (u16*)(ws + 100663296);   // 16 MB  [S][H]

  cast_bf16<<<8192, 256, 0, stream>>>(x, xb, 2097152);
  cast_bf16<<<12288, 256, 0, stream>>>(w_qkv, wqkvb, 3145728);
  cast_bf16<<<4096, 256, 0, stream>>>(w_out, woutb, 1048576);

  gemm8<0><<<384, 512, 0, stream>>>(xb, wqkvb, qb, kb, vtb, 4096, 6144, 2048, 16);
  attn_kernel<<<512, 256, 0, stream>>>(qb, kb, vtb, aob);
  gemm_bt<1><<<32 * 16, 256, 0, stream>>>(aob, woutb, d_out, nullptr, nullptr, 4096, 2048, 2048, 32);
}

// Round 13
// 339.595 us; speedup vs baseline: 1.4373x; 1.0312x over previous
//
#include <hip/hip_runtime.h>
#include <stdint.h>

typedef __attribute__((ext_vector_type(4))) float f32x4;
typedef __attribute__((ext_vector_type(16))) float f32x16;
typedef __attribute__((ext_vector_type(8))) short bf16x8;
typedef unsigned short u16;

#define MFMA(a, b, c) __builtin_amdgcn_mfma_f32_16x16x32_bf16(a, b, c, 0, 0, 0)
#define MFMA32(a, b, c) __builtin_amdgcn_mfma_f32_32x32x16_bf16(a, b, c, 0, 0, 0)
#define EXP2(x) __builtin_amdgcn_exp2f(x)
#define FENCE asm volatile("" ::: "memory")
#define BARRIER do { FENCE; __builtin_amdgcn_s_barrier(); FENCE; } while (0)

__device__ __forceinline__ u16 f2bf(float f) {
  union { float f; unsigned u; } x; x.f = f;
  unsigned r = x.u + 0x7fffu + ((x.u >> 16) & 1u);
  return (u16)(r >> 16);
}

__device__ __forceinline__ unsigned cvtpk(float lo, float hi) {
  unsigned r;
  asm("v_cvt_pk_bf16_f32 %0, %1, %2" : "=v"(r) : "v"(lo), "v"(hi));
  return r;
}

__device__ __forceinline__ void pl32swap(unsigned& a, unsigned& b) {
  asm volatile("v_permlane32_swap_b32 %0, %1" : "+v"(a), "+v"(b));
}

__device__ __forceinline__ void gload16(const void* g, void* l) {
  __builtin_amdgcn_global_load_lds(
      (const __attribute__((address_space(1))) unsigned int*)g,
      (__attribute__((address_space(3))) unsigned int*)l, 16, 0, 0);
}

// ---------------------------------------------------------------- cast f32->bf16
__global__ void __launch_bounds__(256) cast_bf16(const float* __restrict__ in,
                                                 u16* __restrict__ out, int n4) {
  int i = blockIdx.x * 256 + threadIdx.x;
  if (i >= n4) return;
  float4 v = reinterpret_cast<const float4*>(in)[i];
  ushort4 o;
  o.x = f2bf(v.x); o.y = f2bf(v.y); o.z = f2bf(v.z); o.w = f2bf(v.w);
  reinterpret_cast<ushort4*>(out)[i] = o;
}

// ---------------------------------------------------------------- 8-phase 256^2 GEMM (R11, kept)
template <int EPI>
__global__ void __launch_bounds__(512)
gemm8(const u16* __restrict__ A, const u16* __restrict__ B,
      void* __restrict__ C0, void* __restrict__ C1, void* __restrict__ C2,
      int M, int N, int K, int MBt) {
  __shared__ alignas(16) char smb[131072];
  const int tid = threadIdx.x;
  const int w = tid >> 6, lane = tid & 63;
  const int lr = lane & 15, g = lane >> 4;
  const int wm = w >> 2, wn = w & 3;
  const int gb = (blockIdx.x & 7) * ((int)gridDim.x >> 3) + (blockIdx.x >> 3);
  const int mb = gb % MBt, nb = gb / MBt;
  const int m0 = mb * 256, n0 = nb * 256;
  const int NT = K >> 6, NIT = NT >> 1;

  const int l8 = lane >> 3, l7 = lane & 7;
  const int csb = (l7 ^ l8) * 16;
  const char* asrcb[2];
  const char* bsrcb[2];
  unsigned adst[2], bdst[2];
#pragma unroll
  for (int j = 0; j < 2; ++j) {
    int c = 2 * w + j;
    int ra = (c & 7) * 8 + ((c >> 3) << 7) + l8;
    asrcb[j] = (const char*)(A + (size_t)(m0 + ra) * K) + csb;
    adst[j] = (unsigned)(ra * 128 + l7 * 16);
    int rb = (c & 3) * 8 + ((c >> 2) << 6) + l8;
    bsrcb[j] = (const char*)(B + (size_t)(n0 + rb) * K) + csb;
    bdst[j] = (unsigned)(rb * 128 + l7 * 16);
  }
  const size_t arow64 = (size_t)64 * K * 2;
  const size_t brow32 = (size_t)32 * K * 2;

#define STG(kt, u)                                                            \
  do {                                                                        \
    if ((kt) < NT) {                                                          \
      int _d = ((kt) & 1) ? 32768 : 0;                                        \
      size_t _ko = (size_t)(kt) * 128;                                        \
      if ((u) == 0) {                                                         \
        gload16(asrcb[0] + _ko, smb + _d + adst[0]);                          \
        gload16(asrcb[1] + _ko, smb + _d + adst[1]);                          \
      } else if ((u) == 1) {                                                  \
        gload16(bsrcb[0] + _ko, smb + 65536 + _d + bdst[0]);                  \
        gload16(bsrcb[1] + _ko, smb + 65536 + _d + bdst[1]);                  \
      } else if ((u) == 2) {                                                  \
        gload16(asrcb[0] + arow64 + _ko, smb + _d + 8192 + adst[0]);          \
        gload16(asrcb[1] + arow64 + _ko, smb + _d + 8192 + adst[1]);          \
      } else {                                                                \
        gload16(bsrcb[0] + brow32 + _ko, smb + 65536 + _d + 4096 + bdst[0]);  \
        gload16(bsrcb[1] + brow32 + _ko, smb + 65536 + _d + 4096 + bdst[1]);  \
      }                                                                       \
    }                                                                         \
  } while (0)

  f32x4 acc[8][4];
#pragma unroll
  for (int x = 0; x < 8; ++x)
#pragma unroll
    for (int y = 0; y < 4; ++y) acc[x][y] = f32x4{0.f, 0.f, 0.f, 0.f};
  bf16x8 af[4][2], bf01[2][2], bf23[2][2];
  const int aoff0 = ((g) ^ (lr & 7)) << 4;
  const int aoff1 = ((4 + g) ^ (lr & 7)) << 4;
  const int arow = (wm * 128 + lr) * 128;
  const int brow = (wn * 64 + lr) * 128;

  auto LDA = [&](const char* base, int mih) {
#pragma unroll
    for (int mi = 0; mi < 4; ++mi) {
      const char* p = base + arow + (mih * 64 + mi * 16) * 128;
      af[mi][0] = *(const bf16x8*)(p + aoff0);
      af[mi][1] = *(const bf16x8*)(p + aoff1);
    }
  };
  auto LDB = [&](const char* base, bf16x8 (*bfr)[2], int nih) {
#pragma unroll
    for (int ni = 0; ni < 2; ++ni) {
      const char* p = base + brow + (nih * 32 + ni * 16) * 128;
      bfr[ni][0] = *(const bf16x8*)(p + aoff0);
      bfr[ni][1] = *(const bf16x8*)(p + aoff1);
    }
  };
  auto MM = [&](int mih, int nih, bf16x8 (*bfr)[2]) {
    __builtin_amdgcn_s_setprio(1);
#pragma unroll
    for (int mi = 0; mi < 4; ++mi)
#pragma unroll
      for (int ni = 0; ni < 2; ++ni) {
        acc[mih * 4 + mi][nih * 2 + ni] =
            MFMA(af[mi][0], bfr[ni][0], acc[mih * 4 + mi][nih * 2 + ni]);
        acc[mih * 4 + mi][nih * 2 + ni] =
            MFMA(af[mi][1], bfr[ni][1], acc[mih * 4 + mi][nih * 2 + ni]);
      }
    __builtin_amdgcn_s_setprio(0);
  };

  STG(0, 0); STG(0, 1); STG(0, 2); STG(0, 3);
  STG(1, 0); STG(1, 1); STG(1, 2);
  asm volatile("s_waitcnt vmcnt(6)" ::: "memory");
  BARRIER;

  const char* A0 = smb;
  const char* B0 = smb + 65536;
  const char* A1 = smb + 32768;
  const char* B1 = smb + 65536 + 32768;

  for (int it = 0; it < NIT; ++it) {
    const int t0 = 2 * it;
    const bool lastit = (it == NIT - 1);
    LDA(A0, 0); LDB(B0, bf01, 0); STG(t0 + 1, 3);
    BARRIER; MM(0, 0, bf01); BARRIER;
    LDB(B0, bf23, 1); STG(t0 + 2, 0);
    BARRIER; MM(0, 1, bf23); BARRIER;
    LDA(A0, 1); STG(t0 + 2, 1);
    BARRIER; MM(1, 1, bf23); BARRIER;
    STG(t0 + 2, 2);
    if (lastit) asm volatile("s_waitcnt vmcnt(0)" ::: "memory");
    else        asm volatile("s_waitcnt vmcnt(6)" ::: "memory");
    BARRIER; MM(1, 0, bf01); BARRIER;
    LDA(A1, 0); LDB(B1, bf01, 0); STG(t0 + 2, 3);
    BARRIER; MM(0, 0, bf01); BARRIER;
    LDB(B1, bf23, 1); STG(t0 + 3, 0);
    BARRIER; MM(0, 1, bf23); BARRIER;
    LDA(A1, 1); STG(t0 + 3, 1);
    BARRIER; MM(1, 1, bf23); BARRIER;
    STG(t0 + 3, 2);
    asm volatile("s_waitcnt vmcnt(6)" ::: "memory");
    BARRIER; MM(1, 0, bf01); BARRIER;
  }
#undef STG

  if (EPI == 0) {
    const float qs = 0.08838834764831845f * 1.4426950408889634f;
    u16* qo = (u16*)C0;
    u16* ko = (u16*)C1;
    u16* vo = (u16*)C2;
#pragma unroll
    for (int mi = 0; mi < 8; ++mi) {
      int s0 = m0 + wm * 128 + mi * 16 + g * 4;
#pragma unroll
      for (int ni = 0; ni < 4; ++ni) {
        int n = n0 + wn * 64 + ni * 16 + lr;
        int t = n >> 11, hh = (n >> 7) & 15, d = n & 127;
        if (t == 2) {
          ushort4 pk;
          pk.x = f2bf(acc[mi][ni][0]);
          pk.y = f2bf(acc[mi][ni][1]);
          pk.z = f2bf(acc[mi][ni][2]);
          pk.w = f2bf(acc[mi][ni][3]);
          *(ushort4*)(vo + (size_t)(hh * 128 + d) * 4096 + s0) = pk;
        } else {
          float sc = (t == 0) ? qs : 1.f;
          u16* dq = (t == 0 ? qo : ko) + (size_t)(hh * 4096 + s0) * 128 + d;
#pragma unroll
          for (int j = 0; j < 4; ++j) dq[(size_t)j * 128] = f2bf(acc[mi][ni][j] * sc);
        }
      }
    }
  } else {
    float* C = (float*)C0;
#pragma unroll
    for (int mi = 0; mi < 8; ++mi)
#pragma unroll
      for (int ni = 0; ni < 4; ++ni) {
        size_t r0 = (size_t)(m0 + wm * 128 + mi * 16 + g * 4);
        int cn = n0 + wn * 64 + ni * 16 + lr;
#pragma unroll
        for (int j = 0; j < 4; ++j) C[(r0 + j) * N + cn] = acc[mi][ni][j];
      }
  }
}

// ---------------------------------------------------------------- GEMM 128^2 (m97) for out-proj
template <int EPI>
__global__ void __launch_bounds__(256, 2)
gemm_bt(const u16* __restrict__ A, const u16* __restrict__ B,
        void* __restrict__ C0, void* __restrict__ C1, void* __restrict__ C2,
        int M, int N, int K, int MB) {
  __shared__ alignas(16) u16 sm[8192];
  const int tid = threadIdx.x;
  const int w = tid >> 6, lane = tid & 63;
  const int lr = lane & 15, g = lane >> 4;
  const int gb = (blockIdx.x & 7) * ((int)gridDim.x >> 3) + (blockIdx.x >> 3);
  const int mb = gb % MB, nb = gb / MB;
  const int m0 = mb * 128, n0 = nb * 128;

  const u16* src[4];
  u16* dst[4];
#pragma unroll
  for (int i = 0; i < 4; ++i) {
    int c = w * 4 + i;
    int r = (c & 7) * 16 + (lane >> 2);
    int sb = (lane & 3) ^ ((r >> 1) & 3);
    src[i] = (c < 8) ? (A + (size_t)(m0 + r) * K + sb * 8)
                     : (B + (size_t)(n0 + r) * K + sb * 8);
    dst[i] = &sm[c * 512];
  }

  f32x4 acc[4][4];
#pragma unroll
  for (int x = 0; x < 4; ++x)
#pragma unroll
    for (int y = 0; y < 4; ++y) acc[x][y] = f32x4{0.f, 0.f, 0.f, 0.f};

  const int rowb = (w >> 1) * 64, colb = (w & 1) * 64;
  const int nk = K >> 5;
  for (int kt = 0; kt < nk; ++kt) {
#pragma unroll
    for (int i = 0; i < 4; ++i) gload16(src[i] + kt * 32, dst[i]);
    __syncthreads();
    bf16x8 af[4], bfr[4];
#pragma unroll
    for (int mi = 0; mi < 4; ++mi) {
      int r = rowb + mi * 16 + lr;
      af[mi] = *(const bf16x8*)((const char*)sm + r * 64 +
                                ((g * 16) ^ (((r >> 1) & 3) << 4)));
    }
#pragma unroll
    for (int ni = 0; ni < 4; ++ni) {
      int r = colb + ni * 16 + lr;
      bfr[ni] = *(const bf16x8*)((const char*)sm + 8192 + r * 64 +
                                 ((g * 16) ^ (((r >> 1) & 3) << 4)));
    }
#pragma unroll
    for (int mi = 0; mi < 4; ++mi)
#pragma unroll
      for (int ni = 0; ni < 4; ++ni)
        acc[mi][ni] = MFMA(af[mi], bfr[ni], acc[mi][ni]);
    __syncthreads();
  }

  float* C = (float*)C0;
#pragma unroll
  for (int mi = 0; mi < 4; ++mi)
#pragma unroll
    for (int ni = 0; ni < 4; ++ni) {
      size_t r0 = (size_t)(m0 + rowb + mi * 16 + g * 4);
      int cn = n0 + colb + ni * 16 + lr;
#pragma unroll
      for (int j = 0; j < 4; ++j) C[(r0 + j) * N + cn] = acc[mi][ni][j];
    }
}

// ---------------------------------------------------------------- flash attention
// R10 per-wave structure (proven, 96 VGPR) widened to 8 waves / 512 threads:
// one block per CU (grid 256), 256 q rows/block (w*32 each), ONE shared K/V
// staging (waves 0-3 stage K, 4-7 stage V; 4 chunks/wave) -> 2.0 waves/SIMD
// fill the QK->softmax->PV dependency stalls that bounded the 4-wave version.
// Zero-conflict LDS (K row-XOR, V pair-row XOR), dbuf, defer-max, setprio,
// in-register P (cvt_pk+permlane32_swap), O^T accumulate, XCD swizzle.
__global__ void __launch_bounds__(512)
attn_kernel(const u16* __restrict__ qg, const u16* __restrict__ kg,
            const u16* __restrict__ vtg, u16* __restrict__ og) {
  __shared__ alignas(16) u16 sm[32768];  // K dbuf 2x16KB @0, V dbuf 2x16KB @32768B
  const int tid = threadIdx.x;
  const int w = tid >> 6, lane = tid & 63;
  const int ql = lane & 31, hl = lane >> 5;
  const int gb = (blockIdx.x & 7) * 32 + (blockIdx.x >> 3);  // XCD swizzle (256=8*32)
  const int h = gb >> 4;
  const int qb = gb & 15;

  // staging: waves 0-3 -> K tile (chunks 4w..4w+3), waves 4-7 -> V tile
  const u16* ssrc[4];
  u16* sdst[4];
  size_t sstep;
  if (w < 4) {
    sstep = 64 * 128;  // next 64 kv rows
#pragma unroll
    for (int i = 0; i < 4; ++i) {
      int c = w * 4 + i;
      int r = c * 4 + (lane >> 4);           // kv row 0..63 (256B rows)
      int sb = (lane & 15) ^ (r & 15);       // 4-bit XOR (0 conflicts)
      ssrc[i] = kg + (size_t)(h * 4096 + r) * 128 + sb * 8;
      sdst[i] = &sm[c * 512];
    }
  } else {
    sstep = 64;  // next 64 kv columns of v_t
#pragma unroll
    for (int i = 0; i < 4; ++i) {
      int c = (w - 4) * 4 + i;
      int j = c * 4 + (lane >> 4);           // LDS pair-row 0..63 (256B)
      int x = (lane & 15) ^ (j & 15);
      int e = x >> 3, b = x & 7;
      ssrc[i] = vtg + (size_t)(h * 128 + 2 * j + e) * 4096 + b * 8;
      sdst[i] = &sm[16384 + c * 512];
    }
  }

  // Q fragments, B-operand of 32x32x16: lane holds col q=ql, d-slice s = hl*8+(0..7)
  const u16* qrow = qg + (size_t)(h * 4096 + qb * 256 + w * 32 + ql) * 128 + hl * 8;
  bf16x8 qf[8];
#pragma unroll
  for (int s = 0; s < 8; ++s) qf[s] = *(const bf16x8*)(qrow + s * 16);

  f32x16 of[4];
#pragma unroll
  for (int i = 0; i < 4; ++i)
#pragma unroll
    for (int r = 0; r < 16; ++r) of[i][r] = 0.f;
  float mrun = -1e30f, lsum = 0.f;
  const float thr = 6.0f;  // defer-max (exp2 domain): P bounded by 2^6

  // prologue: stage tile 0 into buffer 0
#pragma unroll
  for (int i = 0; i < 4; ++i) gload16(ssrc[i], sdst[i]);

  const int kxor = (ql & 15) << 4;
  const int ve8 = (ql & 1) << 3, vxor = ql >> 1;
  for (int t = 0; t < 64; ++t) {
    const int cur = t & 1;
    asm volatile("s_waitcnt vmcnt(0)" ::: "memory");
    __builtin_amdgcn_s_barrier();
    FENCE;
    if (t + 1 < 64) {
      const int nb = (t + 1) & 1;
#pragma unroll
      for (int i = 0; i < 4; ++i)
        gload16(ssrc[i] + (size_t)(t + 1) * sstep, sdst[i] + nb * 8192);
    }
    const char* kbuf = (const char*)sm + cur * 16384;
    const char* vbuf = (const char*)sm + 32768 + cur * 16384;

    // S^T = K * Q^T (scores pre-scaled into exp2 domain via Q)
    f32x16 st0, st1;
#pragma unroll
    for (int r = 0; r < 16; ++r) { st0[r] = 0.f; st1[r] = 0.f; }
    __builtin_amdgcn_s_setprio(1);
#pragma unroll
    for (int s = 0; s < 8; ++s) {
      int off = ((s * 2 + hl) << 4) ^ kxor;
      bf16x8 k0 = *(const bf16x8*)(kbuf + ql * 256 + off);
      bf16x8 k1 = *(const bf16x8*)(kbuf + (32 + ql) * 256 + off);
      st0 = MFMA32(k0, qf[s], st0);
      st1 = MFMA32(k1, qf[s], st1);
    }
    __builtin_amdgcn_s_setprio(0);

    // online softmax (exp2 domain), q = ql lane-local
    float tmax = -1e30f;
#pragma unroll
    for (int r = 0; r < 16; ++r) tmax = fmaxf(tmax, fmaxf(st0[r], st1[r]));
    tmax = fmaxf(tmax, __shfl_xor(tmax, 32));
    if (!__all(tmax - mrun <= thr)) {  // defer-max
      float mnew = fmaxf(mrun, tmax);
      float esc = EXP2(mrun - mnew);
#pragma unroll
      for (int db = 0; db < 4; ++db)
#pragma unroll
        for (int r = 0; r < 16; ++r) of[db][r] *= esc;
      lsum *= esc;
      mrun = mnew;
    }
    float psum = 0.f;
    unsigned pk0[8], pk1[8];
#pragma unroll
    for (int i = 0; i < 8; ++i) {
      float a0 = EXP2(st0[2 * i] - mrun);
      float b0 = EXP2(st0[2 * i + 1] - mrun);
      float a1 = EXP2(st1[2 * i] - mrun);
      float b1 = EXP2(st1[2 * i + 1] - mrun);
      psum += (a0 + b0) + (a1 + b1);
      pk0[i] = cvtpk(a0, b0);
      pk1[i] = cvtpk(a1, b1);
    }
    psum += __shfl_xor(psum, 32);
    lsum += psum;

    // P^T B-fragments in-register
    pl32swap(pk0[0], pk0[2]); pl32swap(pk0[1], pk0[3]);
    pl32swap(pk0[4], pk0[6]); pl32swap(pk0[5], pk0[7]);
    pl32swap(pk1[0], pk1[2]); pl32swap(pk1[1], pk1[3]);
    pl32swap(pk1[4], pk1[6]); pl32swap(pk1[5], pk1[7]);
    union U { unsigned u[4]; bf16x8 v; };
    U paf[4];
#pragma unroll
    for (int i = 0; i < 4; ++i) { paf[0].u[i] = pk0[i]; paf[1].u[i] = pk0[4 + i]; }
#pragma unroll
    for (int i = 0; i < 4; ++i) { paf[2].u[i] = pk1[i]; paf[3].u[i] = pk1[4 + i]; }

    // O^T += Vt * P^T   (V pair-row layout, 2-way max aliasing)
    __builtin_amdgcn_s_setprio(1);
#pragma unroll
    for (int db = 0; db < 4; ++db) {
      const char* vrow = vbuf + (db * 16 + vxor) * 256;
#pragma unroll
      for (int kp = 0; kp < 4; ++kp) {
        int m = (ve8 | (kp * 2 + hl)) ^ vxor;
        bf16x8 vf = *(const bf16x8*)(vrow + m * 16);
        of[db] = MFMA32(vf, paf[kp].v, of[db]);
      }
    }
    __builtin_amdgcn_s_setprio(0);
    FENCE;
  }

  // epilogue: lane owns q = ql; d = db*32 + (r&3) + 8*(r>>2) + 4*hl
  float linv = 1.f / (lsum + 1e-8f);
  size_t qrow_o = (size_t)(qb * 256 + w * 32 + ql) * 2048 + h * 128;
#pragma unroll
  for (int db = 0; db < 4; ++db)
#pragma unroll
    for (int u = 0; u < 4; ++u) {
      ushort4 pk;
      pk.x = f2bf(of[db][4 * u + 0] * linv);
      pk.y = f2bf(of[db][4 * u + 1] * linv);
      pk.z = f2bf(of[db][4 * u + 2] * linv);
      pk.w = f2bf(of[db][4 * u + 3] * linv);
      *(ushort4*)(og + qrow_o + db * 32 + 8 * u + hl * 4) = pk;
    }
}

// ---------------------------------------------------------------- launcher
extern "C" void kernel_launch(void* const* d_in, const int* in_sizes, int n_in,
                              void* d_out, int out_size, void* d_ws, size_t ws_size,
                              hipStream_t stream) {
  const float* x = (const float*)d_in[0];      // [4096][2048]
  const float* w_qkv = (const float*)d_in[1];  // [6144][2048]
  const float* w_out = (const float*)d_in[2];  // [2048][2048]

  char* ws = (char*)d_ws;
  u16* xb = (u16*)(ws + 0);            // 16 MB
  u16* wqkvb = (u16*)(ws + 16777216);  // 24 MB
  u16* woutb = (u16*)(ws + 41943040);  // 8 MB
  u16* qb = (u16*)(ws + 50331648);     // 16 MB  [NH][S][HD] (pre-scaled)
  u16* kb = (u16*)(ws + 67108864);     // 16 MB  [NH][S][HD]
  u16* vtb = (u16*)(ws + 83886080);    // 16 MB  [NH][HD][S]
  u16* aob = (u16*)(ws + 100663296);   // 16 MB  [S][H]

  cast_bf16<<<8192, 256, 0, stream>>>(x, xb, 2097152);
  cast_bf16<<<12288, 256, 0, stream>>>(w_qkv, wqkvb, 3145728);
  cast_bf16<<<4096, 256, 0, stream>>>(w_out, woutb, 1048576);

  gemm8<0><<<384, 512, 0, stream>>>(xb, wqkvb, qb, kb, vtb, 4096, 6144, 2048, 16);
  attn_kernel<<<256, 512, 0, stream>>>(qb, kb, vtb, aob);
  gemm_bt<1><<<32 * 16, 256, 0, stream>>>(aob, woutb, d_out, nullptr, nullptr, 4096, 2048, 2048, 32);
}